// Round 3
// baseline (1259.910 us; speedup 1.0000x reference)
//
#include <hip/hip_runtime.h>
#include <math.h>

// Problem constants
constexpr int cB   = 4;
constexpr int cT   = 16;
constexpr int cP   = 256;
constexpr int cE   = 768;
constexpr int cH   = 12;
constexpr int cD   = 64;
constexpr int cDFF = 3072;
constexpr int NTOK = cB * cT * cP;        // 16384
constexpr float cSCALE = 0.125f;          // 64^-0.5
constexpr float cEPS = 1e-5f;

typedef __attribute__((ext_vector_type(8))) short short8;
typedef __attribute__((ext_vector_type(4))) float f32x4;
typedef __attribute__((ext_vector_type(8))) unsigned short u16x8;
typedef __attribute__((ext_vector_type(4))) unsigned short u16x4;

#define AS1 __attribute__((address_space(1)))
#define AS3 __attribute__((address_space(3)))

__device__ inline float b2f(unsigned short u) {
    union { unsigned int i; float f; } c; c.i = ((unsigned int)u) << 16; return c.f;
}
__device__ inline unsigned short f2b(float f) {
    union { float f; unsigned int i; } c; c.f = f;
    unsigned int i = c.i;
    unsigned int r = i + 0x7FFFu + ((i >> 16) & 1u);   // RNE
    return (unsigned short)(r >> 16);
}

__device__ inline void gload16(const unsigned short* g, short* l) {
    __builtin_amdgcn_global_load_lds((AS1 const void*)g, (AS3 void*)l, 16, 0, 0);
}

// ---------------------------------------------------------------------------
// MFMA GEMM: C[M,N] = A[M,K](bf16) @ BT[N,K]^T(bf16) + bias
// m97 structure: 128x128 tile, BK=32, 4 waves (2x2), 16x16x32 bf16 MFMA,
// global_load_lds width 16, linear LDS, 2-barrier K-loop.
// OUTB: 1 -> bf16 out, 0 -> fp32 out.  ACT: 1 -> exact GELU.
// ---------------------------------------------------------------------------
template<int OUTB, int ACT>
__global__ __launch_bounds__(256) void gemm_mfma_kernel(
    const unsigned short* __restrict__ A,   // [M][K] bf16
    const unsigned short* __restrict__ BT,  // [N][K] bf16
    const float* __restrict__ bias,         // [N]
    void* __restrict__ Cout,
    int M, int N, int K)
{
    __shared__ short As[4096];   // [128][32] bf16, linear (gload_lds order)
    __shared__ short Bs[4096];   // [128][32] bf16 (rows = n)

    const int tid = threadIdx.x;
    const int m0 = blockIdx.y * 128;
    const int n0 = blockIdx.x * 128;
    const int w  = tid >> 6;
    const int l  = tid & 63;
    const int wr = w >> 1, wc = w & 1;
    const int l15 = l & 15, l16 = l >> 4;

    f32x4 acc[4][4];
    #pragma unroll
    for (int i = 0; i < 4; ++i)
        #pragma unroll
        for (int j = 0; j < 4; ++j)
            #pragma unroll
            for (int r = 0; r < 4; ++r) acc[i][j][r] = 0.f;

    // staging: thread t loads 8 bf16 (16B): row t/4, k-chunk (t%4)*8
    const int sr = tid >> 2;
    const int sc = (tid & 3) << 3;
    const unsigned short* ga0 = A  + (size_t)(m0 + sr) * K + sc;
    const unsigned short* ga1 = A  + (size_t)(m0 + 64 + sr) * K + sc;
    const unsigned short* gb0 = BT + (size_t)(n0 + sr) * K + sc;
    const unsigned short* gb1 = BT + (size_t)(n0 + 64 + sr) * K + sc;
    short* lA0 = As + tid * 8;
    short* lA1 = As + 2048 + tid * 8;
    short* lB0 = Bs + tid * 8;
    short* lB1 = Bs + 2048 + tid * 8;

    const int aoff = (wr * 64 + l15) * 32 + l16 * 8;   // + mf*16*32
    const int boff = (wc * 64 + l15) * 32 + l16 * 8;   // + nf*16*32

    for (int k0 = 0; k0 < K; k0 += 32) {
        __syncthreads();
        gload16(ga0 + k0, lA0);
        gload16(ga1 + k0, lA1);
        gload16(gb0 + k0, lB0);
        gload16(gb1 + k0, lB1);
        __syncthreads();   // compiler emits vmcnt(0) drain before barrier

        short8 aF[4], bF[4];
        #pragma unroll
        for (int mf = 0; mf < 4; ++mf)
            aF[mf] = *(const short8*)(As + aoff + mf * 512);
        #pragma unroll
        for (int nf = 0; nf < 4; ++nf)
            bF[nf] = *(const short8*)(Bs + boff + nf * 512);
        #pragma unroll
        for (int mf = 0; mf < 4; ++mf)
            #pragma unroll
            for (int nf = 0; nf < 4; ++nf)
                acc[mf][nf] = __builtin_amdgcn_mfma_f32_16x16x32_bf16(
                    aF[mf], bF[nf], acc[mf][nf], 0, 0, 0);
    }

    // epilogue: C/D layout col = lane&15, row = (lane>>4)*4 + reg
    #pragma unroll
    for (int mf = 0; mf < 4; ++mf) {
        #pragma unroll
        for (int nf = 0; nf < 4; ++nf) {
            const int col = n0 + wc * 64 + nf * 16 + l15;
            const float bs = bias[col];
            #pragma unroll
            for (int r = 0; r < 4; ++r) {
                const int row = m0 + wr * 64 + mf * 16 + l16 * 4 + r;
                float v = acc[mf][nf][r] + bs;
                if (ACT) v = 0.5f * v * (1.f + erff(v * 0.70710678118654752f));
                if (OUTB) ((unsigned short*)Cout)[(size_t)row * N + col] = f2b(v);
                else      ((float*)Cout)[(size_t)row * N + col] = v;
            }
        }
    }
}

// ---------------------------------------------------------------------------
// weight prep: W[K][N] fp32 -> WT[N][K] bf16  (32x32 LDS tile transpose)
// ---------------------------------------------------------------------------
__global__ __launch_bounds__(256) void transpose_cast_kernel(
    const float* __restrict__ W, unsigned short* __restrict__ WT,
    int K, int N)
{
    __shared__ float t[32][33];
    const int k0 = blockIdx.y * 32;
    const int n0 = blockIdx.x * 32;
    const int tx = threadIdx.x & 31;
    const int ty4 = (threadIdx.x >> 5) << 2;
    #pragma unroll
    for (int i = 0; i < 4; ++i)
        t[ty4 + i][tx] = W[(size_t)(k0 + ty4 + i) * N + n0 + tx];
    __syncthreads();
    #pragma unroll
    for (int i = 0; i < 4; ++i)
        WT[(size_t)(n0 + ty4 + i) * K + k0 + tx] = f2b(t[tx][ty4 + i]);
}

// fp32 -> bf16 elementwise (n multiple of 4)
__global__ __launch_bounds__(256) void cast_bf16_kernel(
    const float* __restrict__ in, unsigned short* __restrict__ out, int n4)
{
    for (int i = blockIdx.x * blockDim.x + threadIdx.x; i < n4;
         i += gridDim.x * blockDim.x) {
        float4 v = ((const float4*)in)[i];
        u16x4 o;
        o[0] = f2b(v.x); o[1] = f2b(v.y); o[2] = f2b(v.z); o[3] = f2b(v.w);
        *(u16x4*)(out + (size_t)i * 4) = o;
    }
}

// ---------------------------------------------------------------------------
// residual + layernorm: out = LN(X + R) * gamma + beta  (fp32), optional bf16 copy
// ---------------------------------------------------------------------------
__global__ __launch_bounds__(256) void residual_ln_kernel(
    const float* __restrict__ X, const float* __restrict__ R,
    const float* __restrict__ gamma, const float* __restrict__ beta,
    float* __restrict__ out, unsigned short* __restrict__ outb)
{
    const int row = blockIdx.x;
    const size_t off = (size_t)row * cE;
    const int tid = threadIdx.x;

    float v[3];
    float s = 0.f, ss = 0.f;
    #pragma unroll
    for (int i = 0; i < 3; ++i) {
        const int e = tid + i * 256;
        const float t = X[off + e] + R[off + e];
        v[i] = t; s += t; ss += t * t;
    }
    #pragma unroll
    for (int o = 32; o > 0; o >>= 1) {
        s  += __shfl_down(s, o);
        ss += __shfl_down(ss, o);
    }
    __shared__ float rs[4], rss[4];
    const int wid = tid >> 6;
    if ((tid & 63) == 0) { rs[wid] = s; rss[wid] = ss; }
    __syncthreads();
    s  = rs[0] + rs[1] + rs[2] + rs[3];
    ss = rss[0] + rss[1] + rss[2] + rss[3];

    const float mean = s * (1.f / cE);
    const float var  = ss * (1.f / cE) - mean * mean;
    const float inv  = rsqrtf(var + cEPS);
    #pragma unroll
    for (int i = 0; i < 3; ++i) {
        const int e = tid + i * 256;
        const float r = (v[i] - mean) * inv * gamma[e] + beta[e];
        out[off + e] = r;
        if (outb) outb[off + e] = f2b(r);
    }
}

// ---------------------------------------------------------------------------
// Spatial attention (bf16 I/O): per (b,t,h), P=256 queries (1 thread each),
// online softmax over 32-key LDS chunks (fp32 math).
// ---------------------------------------------------------------------------
__global__ __launch_bounds__(256) void spatial_attn_kernel(
    const unsigned short* __restrict__ Q, const unsigned short* __restrict__ K,
    const unsigned short* __restrict__ V, unsigned short* __restrict__ O)
{
    const int bid = blockIdx.x;          // b*T*H + t*H + h
    const int h  = bid % cH;
    const int bt = bid / cH;
    const size_t base = (size_t)bt * cP * cE + h * cD;
    const int p = threadIdx.x;

    float q[cD], o[cD];
    const unsigned short* qp = Q + base + (size_t)p * cE;
    #pragma unroll
    for (int d = 0; d < cD; d += 8) {
        short8 f = *(const short8*)(qp + d);
        #pragma unroll
        for (int j = 0; j < 8; ++j) q[d + j] = b2f((unsigned short)f[j]);
    }
    #pragma unroll
    for (int d = 0; d < cD; ++d) o[d] = 0.f;
    float m = -INFINITY, l = 0.f;

    __shared__ float Ks[32][cD];
    __shared__ float Vs[32][cD];

    for (int c0 = 0; c0 < cP; c0 += 32) {
        __syncthreads();
        {
            const int r  = threadIdx.x >> 3;        // 0..31
            const int d0 = (threadIdx.x & 7) << 3;  // 0,8,...,56
            short8 kv = *(const short8*)(K + base + (size_t)(c0 + r) * cE + d0);
            short8 vv = *(const short8*)(V + base + (size_t)(c0 + r) * cE + d0);
            #pragma unroll
            for (int j = 0; j < 8; ++j) {
                Ks[r][d0 + j] = b2f((unsigned short)kv[j]);
                Vs[r][d0 + j] = b2f((unsigned short)vv[j]);
            }
        }
        __syncthreads();

        float sreg[32];
        float cm = -INFINITY;
        #pragma unroll
        for (int j = 0; j < 32; ++j) {
            float acc = 0.f;
            #pragma unroll
            for (int d = 0; d < cD; d += 4) {
                float4 kv = *(const float4*)&Ks[j][d];
                acc = fmaf(q[d], kv.x, acc);   acc = fmaf(q[d+1], kv.y, acc);
                acc = fmaf(q[d+2], kv.z, acc); acc = fmaf(q[d+3], kv.w, acc);
            }
            acc *= cSCALE;
            sreg[j] = acc;
            cm = fmaxf(cm, acc);
        }
        const float mnew  = fmaxf(m, cm);
        const float alpha = __expf(m - mnew);
        l *= alpha;
        #pragma unroll
        for (int d = 0; d < cD; ++d) o[d] *= alpha;
        #pragma unroll
        for (int j = 0; j < 32; ++j) {
            const float pj = __expf(sreg[j] - mnew);
            l += pj;
            #pragma unroll
            for (int d = 0; d < cD; d += 4) {
                float4 vv = *(const float4*)&Vs[j][d];
                o[d]   = fmaf(pj, vv.x, o[d]);
                o[d+1] = fmaf(pj, vv.y, o[d+1]);
                o[d+2] = fmaf(pj, vv.z, o[d+2]);
                o[d+3] = fmaf(pj, vv.w, o[d+3]);
            }
        }
        m = mnew;
    }
    const float invl = 1.f / l;
    unsigned short* op = O + base + (size_t)p * cE;
    #pragma unroll
    for (int d = 0; d < cD; d += 8) {
        u16x8 f;
        #pragma unroll
        for (int j = 0; j < 8; ++j) f[j] = f2b(o[d + j] * invl);
        *(u16x8*)(op + d) = f;
    }
}

// ---------------------------------------------------------------------------
// Temporal causal attention (bf16 I/O): per (b,p,head-group of 6). T=16.
// ---------------------------------------------------------------------------
__global__ __launch_bounds__(128) void temporal_attn_kernel(
    const unsigned short* __restrict__ Q, const unsigned short* __restrict__ Kb,
    const unsigned short* __restrict__ V, unsigned short* __restrict__ O)
{
    const int bid = blockIdx.x;          // (b*P + p)*2 + hg
    const int hg  = bid & 1;
    const int bp  = bid >> 1;
    const int p   = bp % cP;
    const int b   = bp / cP;

    __shared__ float Ks[cT][6][cD + 1];
    __shared__ float Vs[cT][6][cD + 1];

    const size_t framestride = (size_t)cP * cE;
    const size_t base0 = ((size_t)(b * cT) * cP + p) * cE + hg * 384;

    for (int li = threadIdx.x; li < cT * 384; li += 128) {
        const int s = li / 384;
        const int r = li % 384;
        const size_t src = base0 + (size_t)s * framestride + r;
        Ks[s][r / 64][r & 63] = b2f(Kb[src]);
        Vs[s][r / 64][r & 63] = b2f(V[src]);
    }
    __syncthreads();
    if (threadIdx.x >= 96) return;

    const int hh = threadIdx.x >> 4;     // 0..5
    const int t  = threadIdx.x & 15;     // query frame
    const size_t qoff = ((size_t)(b * cT + t) * cP + p) * cE + hg * 384 + hh * cD;

    float q[cD];
    #pragma unroll
    for (int d = 0; d < cD; d += 8) {
        short8 f = *(const short8*)(Q + qoff + d);
        #pragma unroll
        for (int j = 0; j < 8; ++j) q[d + j] = b2f((unsigned short)f[j]);
    }

    float sc[cT];
    float mx = -INFINITY;
    #pragma unroll
    for (int s = 0; s < cT; ++s) {
        float acc = 0.f;
        #pragma unroll
        for (int d = 0; d < cD; ++d) acc = fmaf(q[d], Ks[s][hh][d], acc);
        sc[s] = (s <= t) ? acc * cSCALE : -INFINITY;
        mx = fmaxf(mx, sc[s]);
    }
    float l = 0.f;
    #pragma unroll
    for (int s = 0; s < cT; ++s) {
        const float e_ = __expf(sc[s] - mx);
        sc[s] = e_;
        l += e_;
    }
    float o[cD];
    #pragma unroll
    for (int d = 0; d < cD; ++d) o[d] = 0.f;
    #pragma unroll
    for (int s = 0; s < cT; ++s) {
        const float pj = sc[s];
        #pragma unroll
        for (int d = 0; d < cD; ++d) o[d] = fmaf(pj, Vs[s][hh][d], o[d]);
    }
    const float invl = 1.f / l;
    unsigned short* op = O + qoff;
    #pragma unroll
    for (int d = 0; d < cD; d += 8) {
        u16x8 f;
        #pragma unroll
        for (int j = 0; j < 8; ++j) f[j] = f2b(o[d + j] * invl);
        *(u16x8*)(op + d) = f;
    }
}

// ---------------------------------------------------------------------------
extern "C" void kernel_launch(void* const* d_in, const int* in_sizes, int n_in,
                              void* d_out, int out_size, void* d_ws, size_t ws_size,
                              hipStream_t stream)
{
    const float* x    = (const float*)d_in[0];
    const float* sq_w = (const float*)d_in[1];
    const float* sk_w = (const float*)d_in[2];
    const float* sv_w = (const float*)d_in[3];
    const float* so_w = (const float*)d_in[4];
    const float* sq_b = (const float*)d_in[5];
    const float* sk_b = (const float*)d_in[6];
    const float* sv_b = (const float*)d_in[7];
    const float* so_b = (const float*)d_in[8];
    const float* sg   = (const float*)d_in[9];
    const float* sb   = (const float*)d_in[10];
    const float* tq_w = (const float*)d_in[11];
    const float* tk_w = (const float*)d_in[12];
    const float* tv_w = (const float*)d_in[13];
    const float* to_w = (const float*)d_in[14];
    const float* tq_b = (const float*)d_in[15];
    const float* tk_b = (const float*)d_in[16];
    const float* tv_b = (const float*)d_in[17];
    const float* to_b = (const float*)d_in[18];
    const float* tg   = (const float*)d_in[19];
    const float* tb   = (const float*)d_in[20];
    const float* w1   = (const float*)d_in[21];
    const float* b1   = (const float*)d_in[22];
    const float* w2   = (const float*)d_in[23];
    const float* b2   = (const float*)d_in[24];
    const float* g    = (const float*)d_in[25];
    const float* bb   = (const float*)d_in[26];

    const size_t NE = (size_t)NTOK * cE;   // 12.58M elements
    const size_t EE = (size_t)cE * cE;     // 589824

    // workspace layout (~245 MB)
    float* W0 = (float*)d_ws;                    // fp32 residual stream [NE]
    float* Wp = W0 + NE;                         // fp32 proj / ffn out  [NE]
    unsigned short* Xb = (unsigned short*)(Wp + NE);  // bf16 x_cur [NE]
    unsigned short* Qb = Xb + NE;
    unsigned short* Kbuf = Qb + NE;
    unsigned short* Vb = Kbuf + NE;
    unsigned short* Ob = Vb + NE;
    unsigned short* Hb = Qb;                     // bf16 hidden [NTOK*DFF] overlays Qb..Ob
    unsigned short* WT = Ob + NE;                // bf16 transposed weights
    unsigned short* sqT = WT;
    unsigned short* skT = sqT + EE;
    unsigned short* svT = skT + EE;
    unsigned short* soT = svT + EE;
    unsigned short* tqT = soT + EE;
    unsigned short* tkT = tqT + EE;
    unsigned short* tvT = tkT + EE;
    unsigned short* toT = tvT + EE;
    unsigned short* w1T = toT + EE;              // [DFF][E]
    unsigned short* w2T = w1T + (size_t)cDFF * cE;  // [E][DFF]

    const dim3 blk(256);
    const dim3 gEE(cE / 32, cE / 32);
    const dim3 gLN(NTOK);
    const dim3 gProj(cE / 128, NTOK / 128);      // (6, 128)
    const dim3 gFF1(cDFF / 128, NTOK / 128);     // (24, 128)

    // ---- prep: cast x, transpose+cast all weights to bf16 [N][K] ----
    cast_bf16_kernel<<<dim3(2048), blk, 0, stream>>>(x, Xb, (int)(NE / 4));
    transpose_cast_kernel<<<gEE, blk, 0, stream>>>(sq_w, sqT, cE, cE);
    transpose_cast_kernel<<<gEE, blk, 0, stream>>>(sk_w, skT, cE, cE);
    transpose_cast_kernel<<<gEE, blk, 0, stream>>>(sv_w, svT, cE, cE);
    transpose_cast_kernel<<<gEE, blk, 0, stream>>>(so_w, soT, cE, cE);
    transpose_cast_kernel<<<gEE, blk, 0, stream>>>(tq_w, tqT, cE, cE);
    transpose_cast_kernel<<<gEE, blk, 0, stream>>>(tk_w, tkT, cE, cE);
    transpose_cast_kernel<<<gEE, blk, 0, stream>>>(tv_w, tvT, cE, cE);
    transpose_cast_kernel<<<gEE, blk, 0, stream>>>(to_w, toT, cE, cE);
    transpose_cast_kernel<<<dim3(cDFF / 32, cE / 32), blk, 0, stream>>>(w1, w1T, cE, cDFF);
    transpose_cast_kernel<<<dim3(cE / 32, cDFF / 32), blk, 0, stream>>>(w2, w2T, cDFF, cE);

    // ---- Spatial attention block ----
    gemm_mfma_kernel<1,0><<<gProj, blk, 0, stream>>>(Xb, sqT, sq_b, Qb, NTOK, cE, cE);
    gemm_mfma_kernel<1,0><<<gProj, blk, 0, stream>>>(Xb, skT, sk_b, Kbuf, NTOK, cE, cE);
    gemm_mfma_kernel<1,0><<<gProj, blk, 0, stream>>>(Xb, svT, sv_b, Vb, NTOK, cE, cE);
    spatial_attn_kernel<<<dim3(cB * cT * cH), blk, 0, stream>>>(Qb, Kbuf, Vb, Ob);
    gemm_mfma_kernel<0,0><<<gProj, blk, 0, stream>>>(Ob, soT, so_b, Wp, NTOK, cE, cE);
    residual_ln_kernel<<<gLN, blk, 0, stream>>>(x, Wp, sg, sb, W0, Xb);

    // ---- Temporal attention block ----
    gemm_mfma_kernel<1,0><<<gProj, blk, 0, stream>>>(Xb, tqT, tq_b, Qb, NTOK, cE, cE);
    gemm_mfma_kernel<1,0><<<gProj, blk, 0, stream>>>(Xb, tkT, tk_b, Kbuf, NTOK, cE, cE);
    gemm_mfma_kernel<1,0><<<gProj, blk, 0, stream>>>(Xb, tvT, tv_b, Vb, NTOK, cE, cE);
    temporal_attn_kernel<<<dim3(cB * cP * 2), dim3(128), 0, stream>>>(Qb, Kbuf, Vb, Ob);
    gemm_mfma_kernel<0,0><<<gProj, blk, 0, stream>>>(Ob, toT, to_b, Wp, NTOK, cE, cE);
    residual_ln_kernel<<<gLN, blk, 0, stream>>>(W0, Wp, tg, tb, W0, Xb);

    // ---- FFN ----
    gemm_mfma_kernel<1,1><<<gFF1, blk, 0, stream>>>(Xb, w1T, b1, Hb, NTOK, cDFF, cE);
    gemm_mfma_kernel<0,0><<<gProj, blk, 0, stream>>>(Hb, w2T, b2, Wp, NTOK, cE, cDFF);
    residual_ln_kernel<<<gLN, blk, 0, stream>>>(W0, Wp, g, bb, (float*)d_out, nullptr);
}

// Round 4
// 838.098 us; speedup vs baseline: 1.5033x; 1.5033x over previous
//
#include <hip/hip_runtime.h>
#include <math.h>

// Problem constants
constexpr int cB   = 4;
constexpr int cT   = 16;
constexpr int cP   = 256;
constexpr int cE   = 768;
constexpr int cH   = 12;
constexpr int cD   = 64;
constexpr int cDFF = 3072;
constexpr int NTOK = cB * cT * cP;        // 16384
constexpr float cSCALE = 0.125f;          // 64^-0.5
constexpr float cEPS = 1e-5f;

typedef __attribute__((ext_vector_type(8))) short short8;
typedef __attribute__((ext_vector_type(4))) float f32x4;
typedef __attribute__((ext_vector_type(8))) unsigned short u16x8;
typedef __attribute__((ext_vector_type(4))) unsigned short u16x4;

#define AS1 __attribute__((address_space(1)))
#define AS3 __attribute__((address_space(3)))

__device__ inline float b2f(unsigned short u) {
    union { unsigned int i; float f; } c; c.i = ((unsigned int)u) << 16; return c.f;
}
__device__ inline unsigned short f2b(float f) {
    union { float f; unsigned int i; } c; c.f = f;
    unsigned int i = c.i;
    unsigned int r = i + 0x7FFFu + ((i >> 16) & 1u);   // RNE
    return (unsigned short)(r >> 16);
}

__device__ inline void gload16(const unsigned short* g, short* l) {
    __builtin_amdgcn_global_load_lds((AS1 const void*)g, (AS3 void*)l, 16, 0, 0);
}

// ---------------------------------------------------------------------------
// MFMA GEMM: C[M,N] = A[M,K](bf16) @ BT[N,K]^T(bf16) + bias
// m97 structure: 128x128 tile, BK=32, 4 waves (2x2), 16x16x32 bf16 MFMA,
// global_load_lds width 16, linear LDS, 2-barrier K-loop.
// OUTB: 1 -> bf16 out, 0 -> fp32 out.  ACT: 1 -> exact GELU.
// ---------------------------------------------------------------------------
template<int OUTB, int ACT>
__global__ __launch_bounds__(256) void gemm_mfma_kernel(
    const unsigned short* __restrict__ A,   // [M][K] bf16
    const unsigned short* __restrict__ BT,  // [N][K] bf16
    const float* __restrict__ bias,         // [N]
    void* __restrict__ Cout,
    int M, int N, int K)
{
    __shared__ short As[4096];   // [128][32] bf16, linear (gload_lds order)
    __shared__ short Bs[4096];   // [128][32] bf16 (rows = n)

    const int tid = threadIdx.x;
    const int m0 = blockIdx.y * 128;
    const int n0 = blockIdx.x * 128;
    const int w  = tid >> 6;
    const int l  = tid & 63;
    const int wr = w >> 1, wc = w & 1;
    const int l15 = l & 15, l16 = l >> 4;

    f32x4 acc[4][4];
    #pragma unroll
    for (int i = 0; i < 4; ++i)
        #pragma unroll
        for (int j = 0; j < 4; ++j)
            #pragma unroll
            for (int r = 0; r < 4; ++r) acc[i][j][r] = 0.f;

    // staging: thread t loads 8 bf16 (16B): row t/4, k-chunk (t%4)*8
    const int sr = tid >> 2;
    const int sc = (tid & 3) << 3;
    const unsigned short* ga0 = A  + (size_t)(m0 + sr) * K + sc;
    const unsigned short* ga1 = A  + (size_t)(m0 + 64 + sr) * K + sc;
    const unsigned short* gb0 = BT + (size_t)(n0 + sr) * K + sc;
    const unsigned short* gb1 = BT + (size_t)(n0 + 64 + sr) * K + sc;
    short* lA0 = As + tid * 8;
    short* lA1 = As + 2048 + tid * 8;
    short* lB0 = Bs + tid * 8;
    short* lB1 = Bs + 2048 + tid * 8;

    const int aoff = (wr * 64 + l15) * 32 + l16 * 8;   // + mf*16*32
    const int boff = (wc * 64 + l15) * 32 + l16 * 8;   // + nf*16*32

    for (int k0 = 0; k0 < K; k0 += 32) {
        __syncthreads();
        gload16(ga0 + k0, lA0);
        gload16(ga1 + k0, lA1);
        gload16(gb0 + k0, lB0);
        gload16(gb1 + k0, lB1);
        __syncthreads();   // compiler emits vmcnt(0) drain before barrier

        short8 aF[4], bF[4];
        #pragma unroll
        for (int mf = 0; mf < 4; ++mf)
            aF[mf] = *(const short8*)(As + aoff + mf * 512);
        #pragma unroll
        for (int nf = 0; nf < 4; ++nf)
            bF[nf] = *(const short8*)(Bs + boff + nf * 512);
        #pragma unroll
        for (int mf = 0; mf < 4; ++mf)
            #pragma unroll
            for (int nf = 0; nf < 4; ++nf)
                acc[mf][nf] = __builtin_amdgcn_mfma_f32_16x16x32_bf16(
                    aF[mf], bF[nf], acc[mf][nf], 0, 0, 0);
    }

    // epilogue: C/D layout col = lane&15, row = (lane>>4)*4 + reg
    #pragma unroll
    for (int mf = 0; mf < 4; ++mf) {
        #pragma unroll
        for (int nf = 0; nf < 4; ++nf) {
            const int col = n0 + wc * 64 + nf * 16 + l15;
            const float bs = bias[col];
            #pragma unroll
            for (int r = 0; r < 4; ++r) {
                const int row = m0 + wr * 64 + mf * 16 + l16 * 4 + r;
                float v = acc[mf][nf][r] + bs;
                if (ACT) v = 0.5f * v * (1.f + erff(v * 0.70710678118654752f));
                if (OUTB) ((unsigned short*)Cout)[(size_t)row * N + col] = f2b(v);
                else      ((float*)Cout)[(size_t)row * N + col] = v;
            }
        }
    }
}

// ---------------------------------------------------------------------------
// weight prep: W[K][N] fp32 -> WT[N][K] bf16  (32x32 LDS tile transpose)
// ---------------------------------------------------------------------------
__global__ __launch_bounds__(256) void transpose_cast_kernel(
    const float* __restrict__ W, unsigned short* __restrict__ WT,
    int K, int N)
{
    __shared__ float t[32][33];
    const int k0 = blockIdx.y * 32;
    const int n0 = blockIdx.x * 32;
    const int tx = threadIdx.x & 31;
    const int ty4 = (threadIdx.x >> 5) << 2;
    #pragma unroll
    for (int i = 0; i < 4; ++i)
        t[ty4 + i][tx] = W[(size_t)(k0 + ty4 + i) * N + n0 + tx];
    __syncthreads();
    #pragma unroll
    for (int i = 0; i < 4; ++i)
        WT[(size_t)(n0 + ty4 + i) * K + k0 + tx] = f2b(t[tx][ty4 + i]);
}

// fp32 -> bf16 elementwise (n multiple of 4)
__global__ __launch_bounds__(256) void cast_bf16_kernel(
    const float* __restrict__ in, unsigned short* __restrict__ out, int n4)
{
    for (int i = blockIdx.x * blockDim.x + threadIdx.x; i < n4;
         i += gridDim.x * blockDim.x) {
        float4 v = ((const float4*)in)[i];
        u16x4 o;
        o[0] = f2b(v.x); o[1] = f2b(v.y); o[2] = f2b(v.z); o[3] = f2b(v.w);
        *(u16x4*)(out + (size_t)i * 4) = o;
    }
}

// ---------------------------------------------------------------------------
// residual + layernorm: out = LN(X + R) * gamma + beta  (fp32), optional bf16 copy
// ---------------------------------------------------------------------------
__global__ __launch_bounds__(256) void residual_ln_kernel(
    const float* __restrict__ X, const float* __restrict__ R,
    const float* __restrict__ gamma, const float* __restrict__ beta,
    float* __restrict__ out, unsigned short* __restrict__ outb)
{
    const int row = blockIdx.x;
    const size_t off = (size_t)row * cE;
    const int tid = threadIdx.x;

    float v[3];
    float s = 0.f, ss = 0.f;
    #pragma unroll
    for (int i = 0; i < 3; ++i) {
        const int e = tid + i * 256;
        const float t = X[off + e] + R[off + e];
        v[i] = t; s += t; ss += t * t;
    }
    #pragma unroll
    for (int o = 32; o > 0; o >>= 1) {
        s  += __shfl_down(s, o);
        ss += __shfl_down(ss, o);
    }
    __shared__ float rs[4], rss[4];
    const int wid = tid >> 6;
    if ((tid & 63) == 0) { rs[wid] = s; rss[wid] = ss; }
    __syncthreads();
    s  = rs[0] + rs[1] + rs[2] + rs[3];
    ss = rss[0] + rss[1] + rss[2] + rss[3];

    const float mean = s * (1.f / cE);
    const float var  = ss * (1.f / cE) - mean * mean;
    const float inv  = rsqrtf(var + cEPS);
    #pragma unroll
    for (int i = 0; i < 3; ++i) {
        const int e = tid + i * 256;
        const float r = (v[i] - mean) * inv * gamma[e] + beta[e];
        out[off + e] = r;
        if (outb) outb[off + e] = f2b(r);
    }
}

// ---------------------------------------------------------------------------
// Spatial attention, MFMA flash version.
// 1 block per (b,t,h); 4 waves, wave w owns query rows [w*64, w*64+64).
// KV chunks of 64. K staged via global_load_lds with pre-swizzled source
// (XOR byte ^= (row&7)<<4); V transposed into Vt[d][j] (swizzled);
// P -> per-wave swizzled LDS -> PV A-frags. Online softmax, fp32 stats.
// ---------------------------------------------------------------------------
__global__ __launch_bounds__(256) void spatial_attn_mfma_kernel(
    const unsigned short* __restrict__ Q, const unsigned short* __restrict__ K,
    const unsigned short* __restrict__ V, unsigned short* __restrict__ O)
{
    __shared__ short Ks[64 * 64];      // [j][d] swizzled, row 128B
    __shared__ short Vt[64 * 64];      // [d][j] swizzled
    __shared__ short Ps[4][64 * 64];   // per-wave [q][j] swizzled

    const int bid = blockIdx.x;        // b*T*H + t*H + h
    const int h  = bid % cH;
    const int bt = bid / cH;
    const size_t base = (size_t)bt * cP * cE + h * cD;

    const int tid = threadIdx.x;
    const int w = tid >> 6, l = tid & 63;
    const int l15 = l & 15, l16 = l >> 4;

    // Q A-fragments: row q = w*64+mf*16+l15, k d = kf*32+l16*8
    short8 qf[4][2];
    #pragma unroll
    for (int mf = 0; mf < 4; ++mf)
        #pragma unroll
        for (int kf = 0; kf < 2; ++kf)
            qf[mf][kf] = *(const short8*)(
                Q + base + (size_t)(w * 64 + mf * 16 + l15) * cE + kf * 32 + l16 * 8);

    f32x4 o[4][4];                     // [mf][df]
    float mrun[4][4], lrun[4][4];      // [mf][r]
    #pragma unroll
    for (int mf = 0; mf < 4; ++mf)
        #pragma unroll
        for (int j = 0; j < 4; ++j) {
            #pragma unroll
            for (int r = 0; r < 4; ++r) o[mf][j][r] = 0.f;
            mrun[mf][j] = -INFINITY; lrun[mf][j] = 0.f;
        }

    const int krow = w * 8 + (l >> 3);   // K-stage row (pass adds 32)
    const int kc16 = l & 7;              // 16B slot within row
    const int vj  = tid & 31;            // V-stage j within half
    const int vd0 = (tid >> 5) * 8;      // V-stage d0

    for (int c0 = 0; c0 < cP; c0 += 64) {
        __syncthreads();
        // ---- stage K (linear LDS dest, pre-swizzled global source) ----
        #pragma unroll
        for (int p = 0; p < 2; ++p) {
            const int row = p * 32 + krow;
            gload16(K + base + (size_t)(c0 + row) * cE + ((kc16 ^ (row & 7)) << 3),
                    Ks + row * 64 + kc16 * 8);
        }
        // ---- stage V transposed ----
        #pragma unroll
        for (int p = 0; p < 2; ++p) {
            const int j = p * 32 + vj;
            short8 vv = *(const short8*)(V + base + (size_t)(c0 + j) * cE + vd0);
            char* vb = (char*)Vt;
            #pragma unroll
            for (int e = 0; e < 8; ++e) {
                const int row = vd0 + e;
                *(short*)(vb + row * 128 + ((2 * j) ^ ((row & 7) << 4))) = vv[e];
            }
        }
        __syncthreads();

        // ---- QK^T ----
        f32x4 s[4][4];
        #pragma unroll
        for (int mf = 0; mf < 4; ++mf)
            #pragma unroll
            for (int nf = 0; nf < 4; ++nf)
                #pragma unroll
                for (int r = 0; r < 4; ++r) s[mf][nf][r] = 0.f;

        #pragma unroll
        for (int nf = 0; nf < 4; ++nf) {
            const int row = nf * 16 + l15;
            const char* kb = (const char*)Ks + row * 128;
            const int sw = (row & 7) << 4;
            short8 k0 = *(const short8*)(kb + ((l16 * 16) ^ sw));
            short8 k1 = *(const short8*)(kb + ((64 + l16 * 16) ^ sw));
            #pragma unroll
            for (int mf = 0; mf < 4; ++mf) {
                s[mf][nf] = __builtin_amdgcn_mfma_f32_16x16x32_bf16(qf[mf][0], k0, s[mf][nf], 0, 0, 0);
                s[mf][nf] = __builtin_amdgcn_mfma_f32_16x16x32_bf16(qf[mf][1], k1, s[mf][nf], 0, 0, 0);
            }
        }

        // ---- online softmax (row = mf*16 + l16*4 + r, cols across nf & l15) ----
        #pragma unroll
        for (int mf = 0; mf < 4; ++mf)
            #pragma unroll
            for (int nf = 0; nf < 4; ++nf)
                #pragma unroll
                for (int r = 0; r < 4; ++r) s[mf][nf][r] *= cSCALE;

        #pragma unroll
        for (int mf = 0; mf < 4; ++mf) {
            #pragma unroll
            for (int r = 0; r < 4; ++r) {
                float rv = fmaxf(fmaxf(s[mf][0][r], s[mf][1][r]),
                                 fmaxf(s[mf][2][r], s[mf][3][r]));
                rv = fmaxf(rv, __shfl_xor(rv, 1));
                rv = fmaxf(rv, __shfl_xor(rv, 2));
                rv = fmaxf(rv, __shfl_xor(rv, 4));
                rv = fmaxf(rv, __shfl_xor(rv, 8));
                const float mn = fmaxf(mrun[mf][r], rv);
                const float al = __expf(mrun[mf][r] - mn);
                mrun[mf][r] = mn;
                float ps = 0.f;
                #pragma unroll
                for (int nf = 0; nf < 4; ++nf) {
                    const float pe = __expf(s[mf][nf][r] - mn);
                    s[mf][nf][r] = pe;
                    ps += pe;
                }
                ps += __shfl_xor(ps, 1);
                ps += __shfl_xor(ps, 2);
                ps += __shfl_xor(ps, 4);
                ps += __shfl_xor(ps, 8);
                lrun[mf][r] = lrun[mf][r] * al + ps;
                #pragma unroll
                for (int df = 0; df < 4; ++df) o[mf][df][r] *= al;
            }
        }

        // ---- P -> LDS (bf16, swizzled) ----
        char* pw = (char*)&Ps[w][0];
        #pragma unroll
        for (int mf = 0; mf < 4; ++mf)
            #pragma unroll
            for (int nf = 0; nf < 4; ++nf)
                #pragma unroll
                for (int r = 0; r < 4; ++r) {
                    const int row = mf * 16 + l16 * 4 + r;
                    *(short*)(pw + row * 128 + (((nf * 16 + l15) * 2) ^ ((row & 7) << 4))) =
                        (short)f2b(s[mf][nf][r]);
                }

        // ---- PV ----
        short8 pa[4][2];
        #pragma unroll
        for (int mf = 0; mf < 4; ++mf) {
            const int prow = mf * 16 + l15;
            const char* pb = (const char*)&Ps[w][0] + prow * 128;
            const int sw = (prow & 7) << 4;
            pa[mf][0] = *(const short8*)(pb + ((l16 * 16) ^ sw));
            pa[mf][1] = *(const short8*)(pb + ((64 + l16 * 16) ^ sw));
        }
        #pragma unroll
        for (int df = 0; df < 4; ++df) {
            const int vrow = df * 16 + l15;
            const char* vbb = (const char*)Vt + vrow * 128;
            const int sw = (vrow & 7) << 4;
            short8 v0 = *(const short8*)(vbb + ((l16 * 16) ^ sw));
            short8 v1 = *(const short8*)(vbb + ((64 + l16 * 16) ^ sw));
            #pragma unroll
            for (int mf = 0; mf < 4; ++mf) {
                o[mf][df] = __builtin_amdgcn_mfma_f32_16x16x32_bf16(pa[mf][0], v0, o[mf][df], 0, 0, 0);
                o[mf][df] = __builtin_amdgcn_mfma_f32_16x16x32_bf16(pa[mf][1], v1, o[mf][df], 0, 0, 0);
            }
        }
    }

    // ---- output ----
    #pragma unroll
    for (int mf = 0; mf < 4; ++mf)
        #pragma unroll
        for (int r = 0; r < 4; ++r) {
            const float inv = 1.f / lrun[mf][r];
            const size_t rowoff = base + (size_t)(w * 64 + mf * 16 + l16 * 4 + r) * cE;
            #pragma unroll
            for (int df = 0; df < 4; ++df)
                O[rowoff + df * 16 + l15] = f2b(o[mf][df][r] * inv);
        }
}

// ---------------------------------------------------------------------------
// Temporal causal attention (bf16 I/O): per (b,p,head-group of 6). T=16.
// ---------------------------------------------------------------------------
__global__ __launch_bounds__(128) void temporal_attn_kernel(
    const unsigned short* __restrict__ Q, const unsigned short* __restrict__ Kb,
    const unsigned short* __restrict__ V, unsigned short* __restrict__ O)
{
    const int bid = blockIdx.x;          // (b*P + p)*2 + hg
    const int hg  = bid & 1;
    const int bp  = bid >> 1;
    const int p   = bp % cP;
    const int b   = bp / cP;

    __shared__ float Ks[cT][6][cD + 1];
    __shared__ float Vs[cT][6][cD + 1];

    const size_t framestride = (size_t)cP * cE;
    const size_t base0 = ((size_t)(b * cT) * cP + p) * cE + hg * 384;

    for (int li = threadIdx.x; li < cT * 384; li += 128) {
        const int s = li / 384;
        const int r = li % 384;
        const size_t src = base0 + (size_t)s * framestride + r;
        Ks[s][r / 64][r & 63] = b2f(Kb[src]);
        Vs[s][r / 64][r & 63] = b2f(V[src]);
    }
    __syncthreads();
    if (threadIdx.x >= 96) return;

    const int hh = threadIdx.x >> 4;     // 0..5
    const int t  = threadIdx.x & 15;     // query frame
    const size_t qoff = ((size_t)(b * cT + t) * cP + p) * cE + hg * 384 + hh * cD;

    float q[cD];
    #pragma unroll
    for (int d = 0; d < cD; d += 8) {
        short8 f = *(const short8*)(Q + qoff + d);
        #pragma unroll
        for (int j = 0; j < 8; ++j) q[d + j] = b2f((unsigned short)f[j]);
    }

    float sc[cT];
    float mx = -INFINITY;
    #pragma unroll
    for (int s = 0; s < cT; ++s) {
        float acc = 0.f;
        #pragma unroll
        for (int d = 0; d < cD; ++d) acc = fmaf(q[d], Ks[s][hh][d], acc);
        sc[s] = (s <= t) ? acc * cSCALE : -INFINITY;
        mx = fmaxf(mx, sc[s]);
    }
    float l = 0.f;
    #pragma unroll
    for (int s = 0; s < cT; ++s) {
        const float e_ = __expf(sc[s] - mx);
        sc[s] = e_;
        l += e_;
    }
    float o[cD];
    #pragma unroll
    for (int d = 0; d < cD; ++d) o[d] = 0.f;
    #pragma unroll
    for (int s = 0; s < cT; ++s) {
        const float pj = sc[s];
        #pragma unroll
        for (int d = 0; d < cD; ++d) o[d] = fmaf(pj, Vs[s][hh][d], o[d]);
    }
    const float invl = 1.f / l;
    unsigned short* op = O + qoff;
    #pragma unroll
    for (int d = 0; d < cD; d += 8) {
        u16x8 f;
        #pragma unroll
        for (int j = 0; j < 8; ++j) f[j] = f2b(o[d + j] * invl);
        *(u16x8*)(op + d) = f;
    }
}

// ---------------------------------------------------------------------------
extern "C" void kernel_launch(void* const* d_in, const int* in_sizes, int n_in,
                              void* d_out, int out_size, void* d_ws, size_t ws_size,
                              hipStream_t stream)
{
    const float* x    = (const float*)d_in[0];
    const float* sq_w = (const float*)d_in[1];
    const float* sk_w = (const float*)d_in[2];
    const float* sv_w = (const float*)d_in[3];
    const float* so_w = (const float*)d_in[4];
    const float* sq_b = (const float*)d_in[5];
    const float* sk_b = (const float*)d_in[6];
    const float* sv_b = (const float*)d_in[7];
    const float* so_b = (const float*)d_in[8];
    const float* sg   = (const float*)d_in[9];
    const float* sb   = (const float*)d_in[10];
    const float* tq_w = (const float*)d_in[11];
    const float* tk_w = (const float*)d_in[12];
    const float* tv_w = (const float*)d_in[13];
    const float* to_w = (const float*)d_in[14];
    const float* tq_b = (const float*)d_in[15];
    const float* tk_b = (const float*)d_in[16];
    const float* tv_b = (const float*)d_in[17];
    const float* to_b = (const float*)d_in[18];
    const float* tg   = (const float*)d_in[19];
    const float* tb   = (const float*)d_in[20];
    const float* w1   = (const float*)d_in[21];
    const float* b1   = (const float*)d_in[22];
    const float* w2   = (const float*)d_in[23];
    const float* b2   = (const float*)d_in[24];
    const float* g    = (const float*)d_in[25];
    const float* bb   = (const float*)d_in[26];

    const size_t NE = (size_t)NTOK * cE;   // 12.58M elements
    const size_t EE = (size_t)cE * cE;     // 589824

    // workspace layout (~245 MB)
    float* W0 = (float*)d_ws;                    // fp32 residual stream [NE]
    float* Wp = W0 + NE;                         // fp32 proj / ffn out  [NE]
    unsigned short* Xb = (unsigned short*)(Wp + NE);  // bf16 x_cur [NE]
    unsigned short* Qb = Xb + NE;
    unsigned short* Kbuf = Qb + NE;
    unsigned short* Vb = Kbuf + NE;
    unsigned short* Ob = Vb + NE;
    unsigned short* Hb = Qb;                     // bf16 hidden [NTOK*DFF] overlays Qb..Ob
    unsigned short* WT = Ob + NE;                // bf16 transposed weights
    unsigned short* sqT = WT;
    unsigned short* skT = sqT + EE;
    unsigned short* svT = skT + EE;
    unsigned short* soT = svT + EE;
    unsigned short* tqT = soT + EE;
    unsigned short* tkT = tqT + EE;
    unsigned short* tvT = tkT + EE;
    unsigned short* toT = tvT + EE;
    unsigned short* w1T = toT + EE;              // [DFF][E]
    unsigned short* w2T = w1T + (size_t)cDFF * cE;  // [E][DFF]

    const dim3 blk(256);
    const dim3 gEE(cE / 32, cE / 32);
    const dim3 gLN(NTOK);
    const dim3 gProj(cE / 128, NTOK / 128);      // (6, 128)
    const dim3 gFF1(cDFF / 128, NTOK / 128);     // (24, 128)

    // ---- prep: cast x, transpose+cast all weights to bf16 [N][K] ----
    cast_bf16_kernel<<<dim3(2048), blk, 0, stream>>>(x, Xb, (int)(NE / 4));
    transpose_cast_kernel<<<gEE, blk, 0, stream>>>(sq_w, sqT, cE, cE);
    transpose_cast_kernel<<<gEE, blk, 0, stream>>>(sk_w, skT, cE, cE);
    transpose_cast_kernel<<<gEE, blk, 0, stream>>>(sv_w, svT, cE, cE);
    transpose_cast_kernel<<<gEE, blk, 0, stream>>>(so_w, soT, cE, cE);
    transpose_cast_kernel<<<gEE, blk, 0, stream>>>(tq_w, tqT, cE, cE);
    transpose_cast_kernel<<<gEE, blk, 0, stream>>>(tk_w, tkT, cE, cE);
    transpose_cast_kernel<<<gEE, blk, 0, stream>>>(tv_w, tvT, cE, cE);
    transpose_cast_kernel<<<gEE, blk, 0, stream>>>(to_w, toT, cE, cE);
    transpose_cast_kernel<<<dim3(cDFF / 32, cE / 32), blk, 0, stream>>>(w1, w1T, cE, cDFF);
    transpose_cast_kernel<<<dim3(cE / 32, cDFF / 32), blk, 0, stream>>>(w2, w2T, cDFF, cE);

    // ---- Spatial attention block ----
    gemm_mfma_kernel<1,0><<<gProj, blk, 0, stream>>>(Xb, sqT, sq_b, Qb, NTOK, cE, cE);
    gemm_mfma_kernel<1,0><<<gProj, blk, 0, stream>>>(Xb, skT, sk_b, Kbuf, NTOK, cE, cE);
    gemm_mfma_kernel<1,0><<<gProj, blk, 0, stream>>>(Xb, svT, sv_b, Vb, NTOK, cE, cE);
    spatial_attn_mfma_kernel<<<dim3(cB * cT * cH), blk, 0, stream>>>(Qb, Kbuf, Vb, Ob);
    gemm_mfma_kernel<0,0><<<gProj, blk, 0, stream>>>(Ob, soT, so_b, Wp, NTOK, cE, cE);
    residual_ln_kernel<<<gLN, blk, 0, stream>>>(x, Wp, sg, sb, W0, Xb);

    // ---- Temporal attention block ----
    gemm_mfma_kernel<1,0><<<gProj, blk, 0, stream>>>(Xb, tqT, tq_b, Qb, NTOK, cE, cE);
    gemm_mfma_kernel<1,0><<<gProj, blk, 0, stream>>>(Xb, tkT, tk_b, Kbuf, NTOK, cE, cE);
    gemm_mfma_kernel<1,0><<<gProj, blk, 0, stream>>>(Xb, tvT, tv_b, Vb, NTOK, cE, cE);
    temporal_attn_kernel<<<dim3(cB * cP * 2), dim3(128), 0, stream>>>(Qb, Kbuf, Vb, Ob);
    gemm_mfma_kernel<0,0><<<gProj, blk, 0, stream>>>(Ob, toT, to_b, Wp, NTOK, cE, cE);
    residual_ln_kernel<<<gLN, blk, 0, stream>>>(W0, Wp, tg, tb, W0, Xb);

    // ---- FFN ----
    gemm_mfma_kernel<1,1><<<gFF1, blk, 0, stream>>>(Xb, w1T, b1, Hb, NTOK, cDFF, cE);
    gemm_mfma_kernel<0,0><<<gProj, blk, 0, stream>>>(Hb, w2T, b2, Wp, NTOK, cE, cDFF);
    residual_ln_kernel<<<gLN, blk, 0, stream>>>(W0, Wp, g, bb, (float*)d_out, nullptr);
}

// Round 5
// 785.815 us; speedup vs baseline: 1.6033x; 1.0665x over previous
//
#include <hip/hip_runtime.h>
#include <math.h>

// Problem constants
constexpr int cB   = 4;
constexpr int cT   = 16;
constexpr int cP   = 256;
constexpr int cE   = 768;
constexpr int cH   = 12;
constexpr int cD   = 64;
constexpr int cDFF = 3072;
constexpr int NTOK = cB * cT * cP;        // 16384
constexpr float cSCALE = 0.125f;          // 64^-0.5
constexpr float cEPS = 1e-5f;

typedef __attribute__((ext_vector_type(8))) short short8;
typedef __attribute__((ext_vector_type(4))) float f32x4;
typedef __attribute__((ext_vector_type(8))) unsigned short u16x8;
typedef __attribute__((ext_vector_type(4))) unsigned short u16x4;

#define AS1 __attribute__((address_space(1)))
#define AS3 __attribute__((address_space(3)))

__device__ inline float b2f(unsigned short u) {
    union { unsigned int i; float f; } c; c.i = ((unsigned int)u) << 16; return c.f;
}
__device__ inline unsigned short f2b(float f) {
    union { float f; unsigned int i; } c; c.f = f;
    unsigned int i = c.i;
    unsigned int r = i + 0x7FFFu + ((i >> 16) & 1u);   // RNE
    return (unsigned short)(r >> 16);
}

__device__ inline void gload16(const unsigned short* g, short* l) {
    __builtin_amdgcn_global_load_lds((AS1 const void*)g, (AS3 void*)l, 16, 0, 0);
}

// ---------------------------------------------------------------------------
// MFMA GEMM: C[M,N] = A[M,K](bf16) @ BT[N,K]^T(bf16) + bias
// 128x128 tile, BK=32, 4 waves (2x2), 16x16x32 bf16 MFMA,
// double-buffered LDS, T3-minimum 2-phase: STAGE(t+1) issued before
// compute(t); single __syncthreads (vmcnt0+barrier) per K-step.
// OUTB: 1 -> bf16 out, 0 -> fp32 out.  ACT: 1 -> exact GELU.
// ---------------------------------------------------------------------------
template<int OUTB, int ACT>
__global__ __launch_bounds__(256) void gemm_mfma_kernel(
    const unsigned short* __restrict__ A,   // [M][K] bf16
    const unsigned short* __restrict__ BT,  // [N][K] bf16
    const float* __restrict__ bias,         // [N]
    void* __restrict__ Cout,
    int M, int N, int K)
{
    __shared__ short As[8192];   // 2 x [128][32] bf16, linear (gload_lds order)
    __shared__ short Bs[8192];   // 2 x [128][32] bf16 (rows = n)

    const int tid = threadIdx.x;
    const int m0 = blockIdx.y * 128;
    const int n0 = blockIdx.x * 128;
    const int w  = tid >> 6;
    const int l  = tid & 63;
    const int wr = w >> 1, wc = w & 1;
    const int l15 = l & 15, l16 = l >> 4;

    f32x4 acc[4][4];
    #pragma unroll
    for (int i = 0; i < 4; ++i)
        #pragma unroll
        for (int j = 0; j < 4; ++j)
            #pragma unroll
            for (int r = 0; r < 4; ++r) acc[i][j][r] = 0.f;

    // staging: thread t loads 8 bf16 (16B): row t/4, k-chunk (t%4)*8
    const int sr = tid >> 2;
    const int sc = (tid & 3) << 3;
    const unsigned short* ga0 = A  + (size_t)(m0 + sr) * K + sc;
    const unsigned short* ga1 = A  + (size_t)(m0 + 64 + sr) * K + sc;
    const unsigned short* gb0 = BT + (size_t)(n0 + sr) * K + sc;
    const unsigned short* gb1 = BT + (size_t)(n0 + 64 + sr) * K + sc;
    short* lA = As + tid * 8;
    short* lB = Bs + tid * 8;

    const int aoff = (wr * 64 + l15) * 32 + l16 * 8;   // + mf*16*32
    const int boff = (wc * 64 + l15) * 32 + l16 * 8;   // + nf*16*32

    // prologue: stage tile 0 into buffer 0
    gload16(ga0, lA);
    gload16(ga1, lA + 2048);
    gload16(gb0, lB);
    gload16(gb1, lB + 2048);
    __syncthreads();          // vmcnt(0) drain + barrier

    int cur = 0;
    for (int k0 = 0; k0 < K; k0 += 32) {
        // issue next-tile prefetch into the other buffer (async)
        if (k0 + 32 < K) {
            const int nb = (cur ^ 1) << 12;
            gload16(ga0 + k0 + 32, lA + nb);
            gload16(ga1 + k0 + 32, lA + nb + 2048);
            gload16(gb0 + k0 + 32, lB + nb);
            gload16(gb1 + k0 + 32, lB + nb + 2048);
        }
        const int cb = cur << 12;
        short8 aF[4], bF[4];
        #pragma unroll
        for (int mf = 0; mf < 4; ++mf)
            aF[mf] = *(const short8*)(As + cb + aoff + mf * 512);
        #pragma unroll
        for (int nf = 0; nf < 4; ++nf)
            bF[nf] = *(const short8*)(Bs + cb + boff + nf * 512);
        #pragma unroll
        for (int mf = 0; mf < 4; ++mf)
            #pragma unroll
            for (int nf = 0; nf < 4; ++nf)
                acc[mf][nf] = __builtin_amdgcn_mfma_f32_16x16x32_bf16(
                    aF[mf], bF[nf], acc[mf][nf], 0, 0, 0);
        __syncthreads();      // drains this iter's prefetch (vmcnt0) + barrier
        cur ^= 1;
    }

    // epilogue: C/D layout col = lane&15, row = (lane>>4)*4 + reg
    #pragma unroll
    for (int mf = 0; mf < 4; ++mf) {
        #pragma unroll
        for (int nf = 0; nf < 4; ++nf) {
            const int col = n0 + wc * 64 + nf * 16 + l15;
            const float bs = bias[col];
            #pragma unroll
            for (int r = 0; r < 4; ++r) {
                const int row = m0 + wr * 64 + mf * 16 + l16 * 4 + r;
                float v = acc[mf][nf][r] + bs;
                if (ACT) v = 0.5f * v * (1.f + erff(v * 0.70710678118654752f));
                if (OUTB) ((unsigned short*)Cout)[(size_t)row * N + col] = f2b(v);
                else      ((float*)Cout)[(size_t)row * N + col] = v;
            }
        }
    }
}

// ---------------------------------------------------------------------------
// weight prep: W[K][N] fp32 -> WT[N][K] bf16  (32x32 LDS tile transpose)
// ---------------------------------------------------------------------------
__global__ __launch_bounds__(256) void transpose_cast_kernel(
    const float* __restrict__ W, unsigned short* __restrict__ WT,
    int K, int N)
{
    __shared__ float t[32][33];
    const int k0 = blockIdx.y * 32;
    const int n0 = blockIdx.x * 32;
    const int tx = threadIdx.x & 31;
    const int ty4 = (threadIdx.x >> 5) << 2;
    #pragma unroll
    for (int i = 0; i < 4; ++i)
        t[ty4 + i][tx] = W[(size_t)(k0 + ty4 + i) * N + n0 + tx];
    __syncthreads();
    #pragma unroll
    for (int i = 0; i < 4; ++i)
        WT[(size_t)(n0 + ty4 + i) * K + k0 + tx] = f2b(t[tx][ty4 + i]);
}

// fused prep for the 8 E x E attention weights (grid.z selects weight)
struct TP8 { const float* src[8]; unsigned short* dst[8]; };
__global__ __launch_bounds__(256) void transpose_cast8_kernel(TP8 p)
{
    __shared__ float t[32][33];
    const int z = blockIdx.z;
    const float* W = p.src[z];
    unsigned short* WT = p.dst[z];
    const int k0 = blockIdx.y * 32;
    const int n0 = blockIdx.x * 32;
    const int tx = threadIdx.x & 31;
    const int ty4 = (threadIdx.x >> 5) << 2;
    #pragma unroll
    for (int i = 0; i < 4; ++i)
        t[ty4 + i][tx] = W[(size_t)(k0 + ty4 + i) * cE + n0 + tx];
    __syncthreads();
    #pragma unroll
    for (int i = 0; i < 4; ++i)
        WT[(size_t)(n0 + ty4 + i) * cE + k0 + tx] = f2b(t[tx][ty4 + i]);
}

// fp32 -> bf16 elementwise (n multiple of 4)
__global__ __launch_bounds__(256) void cast_bf16_kernel(
    const float* __restrict__ in, unsigned short* __restrict__ out, int n4)
{
    for (int i = blockIdx.x * blockDim.x + threadIdx.x; i < n4;
         i += gridDim.x * blockDim.x) {
        float4 v = ((const float4*)in)[i];
        u16x4 o;
        o[0] = f2b(v.x); o[1] = f2b(v.y); o[2] = f2b(v.z); o[3] = f2b(v.w);
        *(u16x4*)(out + (size_t)i * 4) = o;
    }
}

// ---------------------------------------------------------------------------
// residual + layernorm: out = LN(X + R) * gamma + beta  (fp32), optional bf16 copy
// ---------------------------------------------------------------------------
__global__ __launch_bounds__(256) void residual_ln_kernel(
    const float* __restrict__ X, const float* __restrict__ R,
    const float* __restrict__ gamma, const float* __restrict__ beta,
    float* __restrict__ out, unsigned short* __restrict__ outb)
{
    const int row = blockIdx.x;
    const size_t off = (size_t)row * cE;
    const int tid = threadIdx.x;

    float v[3];
    float s = 0.f, ss = 0.f;
    #pragma unroll
    for (int i = 0; i < 3; ++i) {
        const int e = tid + i * 256;
        const float t = X[off + e] + R[off + e];
        v[i] = t; s += t; ss += t * t;
    }
    #pragma unroll
    for (int o = 32; o > 0; o >>= 1) {
        s  += __shfl_down(s, o);
        ss += __shfl_down(ss, o);
    }
    __shared__ float rs[4], rss[4];
    const int wid = tid >> 6;
    if ((tid & 63) == 0) { rs[wid] = s; rss[wid] = ss; }
    __syncthreads();
    s  = rs[0] + rs[1] + rs[2] + rs[3];
    ss = rss[0] + rss[1] + rss[2] + rss[3];

    const float mean = s * (1.f / cE);
    const float var  = ss * (1.f / cE) - mean * mean;
    const float inv  = rsqrtf(var + cEPS);
    #pragma unroll
    for (int i = 0; i < 3; ++i) {
        const int e = tid + i * 256;
        const float r = (v[i] - mean) * inv * gamma[e] + beta[e];
        out[off + e] = r;
        if (outb) outb[off + e] = f2b(r);
    }
}

// ---------------------------------------------------------------------------
// Spatial attention, MFMA flash version.
// 1 block per (b,t,h); 4 waves, wave w owns query rows [w*64, w*64+64).
// KV chunks of 64. K staged via global_load_lds with pre-swizzled source
// (XOR byte ^= (row&7)<<4); V transposed into Vt[d][j] (swizzled);
// P -> per-wave swizzled LDS -> PV A-frags. Online softmax, fp32 stats.
// ---------------------------------------------------------------------------
__global__ __launch_bounds__(256) void spatial_attn_mfma_kernel(
    const unsigned short* __restrict__ Q, const unsigned short* __restrict__ K,
    const unsigned short* __restrict__ V, unsigned short* __restrict__ O)
{
    __shared__ short Ks[64 * 64];      // [j][d] swizzled, row 128B
    __shared__ short Vt[64 * 64];      // [d][j] swizzled
    __shared__ short Ps[4][64 * 64];   // per-wave [q][j] swizzled

    const int bid = blockIdx.x;        // b*T*H + t*H + h
    const int h  = bid % cH;
    const int bt = bid / cH;
    const size_t base = (size_t)bt * cP * cE + h * cD;

    const int tid = threadIdx.x;
    const int w = tid >> 6, l = tid & 63;
    const int l15 = l & 15, l16 = l >> 4;

    // Q A-fragments: row q = w*64+mf*16+l15, k d = kf*32+l16*8
    short8 qf[4][2];
    #pragma unroll
    for (int mf = 0; mf < 4; ++mf)
        #pragma unroll
        for (int kf = 0; kf < 2; ++kf)
            qf[mf][kf] = *(const short8*)(
                Q + base + (size_t)(w * 64 + mf * 16 + l15) * cE + kf * 32 + l16 * 8);

    f32x4 o[4][4];                     // [mf][df]
    float mrun[4][4], lrun[4][4];      // [mf][r]
    #pragma unroll
    for (int mf = 0; mf < 4; ++mf)
        #pragma unroll
        for (int j = 0; j < 4; ++j) {
            #pragma unroll
            for (int r = 0; r < 4; ++r) o[mf][j][r] = 0.f;
            mrun[mf][j] = -INFINITY; lrun[mf][j] = 0.f;
        }

    const int krow = w * 8 + (l >> 3);   // K-stage row (pass adds 32)
    const int kc16 = l & 7;              // 16B slot within row
    const int vj  = tid & 31;            // V-stage j within half
    const int vd0 = (tid >> 5) * 8;      // V-stage d0

    for (int c0 = 0; c0 < cP; c0 += 64) {
        __syncthreads();
        // ---- stage K (linear LDS dest, pre-swizzled global source) ----
        #pragma unroll
        for (int p = 0; p < 2; ++p) {
            const int row = p * 32 + krow;
            gload16(K + base + (size_t)(c0 + row) * cE + ((kc16 ^ (row & 7)) << 3),
                    Ks + row * 64 + kc16 * 8);
        }
        // ---- stage V transposed ----
        #pragma unroll
        for (int p = 0; p < 2; ++p) {
            const int j = p * 32 + vj;
            short8 vv = *(const short8*)(V + base + (size_t)(c0 + j) * cE + vd0);
            char* vb = (char*)Vt;
            #pragma unroll
            for (int e = 0; e < 8; ++e) {
                const int row = vd0 + e;
                *(short*)(vb + row * 128 + ((2 * j) ^ ((row & 7) << 4))) = vv[e];
            }
        }
        __syncthreads();

        // ---- QK^T ----
        f32x4 s[4][4];
        #pragma unroll
        for (int mf = 0; mf < 4; ++mf)
            #pragma unroll
            for (int nf = 0; nf < 4; ++nf)
                #pragma unroll
                for (int r = 0; r < 4; ++r) s[mf][nf][r] = 0.f;

        #pragma unroll
        for (int nf = 0; nf < 4; ++nf) {
            const int row = nf * 16 + l15;
            const char* kb = (const char*)Ks + row * 128;
            const int sw = (row & 7) << 4;
            short8 k0 = *(const short8*)(kb + ((l16 * 16) ^ sw));
            short8 k1 = *(const short8*)(kb + ((64 + l16 * 16) ^ sw));
            #pragma unroll
            for (int mf = 0; mf < 4; ++mf) {
                s[mf][nf] = __builtin_amdgcn_mfma_f32_16x16x32_bf16(qf[mf][0], k0, s[mf][nf], 0, 0, 0);
                s[mf][nf] = __builtin_amdgcn_mfma_f32_16x16x32_bf16(qf[mf][1], k1, s[mf][nf], 0, 0, 0);
            }
        }

        // ---- online softmax (row = mf*16 + l16*4 + r, cols across nf & l15) ----
        #pragma unroll
        for (int mf = 0; mf < 4; ++mf)
            #pragma unroll
            for (int nf = 0; nf < 4; ++nf)
                #pragma unroll
                for (int r = 0; r < 4; ++r) s[mf][nf][r] *= cSCALE;

        #pragma unroll
        for (int mf = 0; mf < 4; ++mf) {
            #pragma unroll
            for (int r = 0; r < 4; ++r) {
                float rv = fmaxf(fmaxf(s[mf][0][r], s[mf][1][r]),
                                 fmaxf(s[mf][2][r], s[mf][3][r]));
                rv = fmaxf(rv, __shfl_xor(rv, 1));
                rv = fmaxf(rv, __shfl_xor(rv, 2));
                rv = fmaxf(rv, __shfl_xor(rv, 4));
                rv = fmaxf(rv, __shfl_xor(rv, 8));
                const float mn = fmaxf(mrun[mf][r], rv);
                const float al = __expf(mrun[mf][r] - mn);
                mrun[mf][r] = mn;
                float ps = 0.f;
                #pragma unroll
                for (int nf = 0; nf < 4; ++nf) {
                    const float pe = __expf(s[mf][nf][r] - mn);
                    s[mf][nf][r] = pe;
                    ps += pe;
                }
                ps += __shfl_xor(ps, 1);
                ps += __shfl_xor(ps, 2);
                ps += __shfl_xor(ps, 4);
                ps += __shfl_xor(ps, 8);
                lrun[mf][r] = lrun[mf][r] * al + ps;
                #pragma unroll
                for (int df = 0; df < 4; ++df) o[mf][df][r] *= al;
            }
        }

        // ---- P -> LDS (bf16, swizzled) ----
        char* pw = (char*)&Ps[w][0];
        #pragma unroll
        for (int mf = 0; mf < 4; ++mf)
            #pragma unroll
            for (int nf = 0; nf < 4; ++nf)
                #pragma unroll
                for (int r = 0; r < 4; ++r) {
                    const int row = mf * 16 + l16 * 4 + r;
                    *(short*)(pw + row * 128 + (((nf * 16 + l15) * 2) ^ ((row & 7) << 4))) =
                        (short)f2b(s[mf][nf][r]);
                }

        // ---- PV ----
        short8 pa[4][2];
        #pragma unroll
        for (int mf = 0; mf < 4; ++mf) {
            const int prow = mf * 16 + l15;
            const char* pb = (const char*)&Ps[w][0] + prow * 128;
            const int sw = (prow & 7) << 4;
            pa[mf][0] = *(const short8*)(pb + ((l16 * 16) ^ sw));
            pa[mf][1] = *(const short8*)(pb + ((64 + l16 * 16) ^ sw));
        }
        #pragma unroll
        for (int df = 0; df < 4; ++df) {
            const int vrow = df * 16 + l15;
            const char* vbb = (const char*)Vt + vrow * 128;
            const int sw = (vrow & 7) << 4;
            short8 v0 = *(const short8*)(vbb + ((l16 * 16) ^ sw));
            short8 v1 = *(const short8*)(vbb + ((64 + l16 * 16) ^ sw));
            #pragma unroll
            for (int mf = 0; mf < 4; ++mf) {
                o[mf][df] = __builtin_amdgcn_mfma_f32_16x16x32_bf16(pa[mf][0], v0, o[mf][df], 0, 0, 0);
                o[mf][df] = __builtin_amdgcn_mfma_f32_16x16x32_bf16(pa[mf][1], v1, o[mf][df], 0, 0, 0);
            }
        }
    }

    // ---- output ----
    #pragma unroll
    for (int mf = 0; mf < 4; ++mf)
        #pragma unroll
        for (int r = 0; r < 4; ++r) {
            const float inv = 1.f / lrun[mf][r];
            const size_t rowoff = base + (size_t)(w * 64 + mf * 16 + l16 * 4 + r) * cE;
            #pragma unroll
            for (int df = 0; df < 4; ++df)
                O[rowoff + df * 16 + l15] = f2b(o[mf][df][r] * inv);
        }
}

// ---------------------------------------------------------------------------
// Temporal causal attention (bf16 I/O): per (b,p,head-group of 6). T=16.
// ---------------------------------------------------------------------------
__global__ __launch_bounds__(128) void temporal_attn_kernel(
    const unsigned short* __restrict__ Q, const unsigned short* __restrict__ Kb,
    const unsigned short* __restrict__ V, unsigned short* __restrict__ O)
{
    const int bid = blockIdx.x;          // (b*P + p)*2 + hg
    const int hg  = bid & 1;
    const int bp  = bid >> 1;
    const int p   = bp % cP;
    const int b   = bp / cP;

    __shared__ float Ks[cT][6][cD + 1];
    __shared__ float Vs[cT][6][cD + 1];

    const size_t framestride = (size_t)cP * cE;
    const size_t base0 = ((size_t)(b * cT) * cP + p) * cE + hg * 384;

    for (int li = threadIdx.x; li < cT * 384; li += 128) {
        const int s = li / 384;
        const int r = li % 384;
        const size_t src = base0 + (size_t)s * framestride + r;
        Ks[s][r / 64][r & 63] = b2f(Kb[src]);
        Vs[s][r / 64][r & 63] = b2f(V[src]);
    }
    __syncthreads();
    if (threadIdx.x >= 96) return;

    const int hh = threadIdx.x >> 4;     // 0..5
    const int t  = threadIdx.x & 15;     // query frame
    const size_t qoff = ((size_t)(b * cT + t) * cP + p) * cE + hg * 384 + hh * cD;

    float q[cD];
    #pragma unroll
    for (int d = 0; d < cD; d += 8) {
        short8 f = *(const short8*)(Q + qoff + d);
        #pragma unroll
        for (int j = 0; j < 8; ++j) q[d + j] = b2f((unsigned short)f[j]);
    }

    float sc[cT];
    float mx = -INFINITY;
    #pragma unroll
    for (int s = 0; s < cT; ++s) {
        float acc = 0.f;
        #pragma unroll
        for (int d = 0; d < cD; ++d) acc = fmaf(q[d], Ks[s][hh][d], acc);
        sc[s] = (s <= t) ? acc * cSCALE : -INFINITY;
        mx = fmaxf(mx, sc[s]);
    }
    float l = 0.f;
    #pragma unroll
    for (int s = 0; s < cT; ++s) {
        const float e_ = __expf(sc[s] - mx);
        sc[s] = e_;
        l += e_;
    }
    float o[cD];
    #pragma unroll
    for (int d = 0; d < cD; ++d) o[d] = 0.f;
    #pragma unroll
    for (int s = 0; s < cT; ++s) {
        const float pj = sc[s];
        #pragma unroll
        for (int d = 0; d < cD; ++d) o[d] = fmaf(pj, Vs[s][hh][d], o[d]);
    }
    const float invl = 1.f / l;
    unsigned short* op = O + qoff;
    #pragma unroll
    for (int d = 0; d < cD; d += 8) {
        u16x8 f;
        #pragma unroll
        for (int j = 0; j < 8; ++j) f[j] = f2b(o[d + j] * invl);
        *(u16x8*)(op + d) = f;
    }
}

// ---------------------------------------------------------------------------
extern "C" void kernel_launch(void* const* d_in, const int* in_sizes, int n_in,
                              void* d_out, int out_size, void* d_ws, size_t ws_size,
                              hipStream_t stream)
{
    const float* x    = (const float*)d_in[0];
    const float* sq_w = (const float*)d_in[1];
    const float* sk_w = (const float*)d_in[2];
    const float* sv_w = (const float*)d_in[3];
    const float* so_w = (const float*)d_in[4];
    const float* sq_b = (const float*)d_in[5];
    const float* sk_b = (const float*)d_in[6];
    const float* sv_b = (const float*)d_in[7];
    const float* so_b = (const float*)d_in[8];
    const float* sg   = (const float*)d_in[9];
    const float* sb   = (const float*)d_in[10];
    const float* tq_w = (const float*)d_in[11];
    const float* tk_w = (const float*)d_in[12];
    const float* tv_w = (const float*)d_in[13];
    const float* to_w = (const float*)d_in[14];
    const float* tq_b = (const float*)d_in[15];
    const float* tk_b = (const float*)d_in[16];
    const float* tv_b = (const float*)d_in[17];
    const float* to_b = (const float*)d_in[18];
    const float* tg   = (const float*)d_in[19];
    const float* tb   = (const float*)d_in[20];
    const float* w1   = (const float*)d_in[21];
    const float* b1   = (const float*)d_in[22];
    const float* w2   = (const float*)d_in[23];
    const float* b2   = (const float*)d_in[24];
    const float* g    = (const float*)d_in[25];
    const float* bb   = (const float*)d_in[26];

    const size_t NE = (size_t)NTOK * cE;   // 12.58M elements
    const size_t EE = (size_t)cE * cE;     // 589824

    // workspace layout (~245 MB)
    float* W0 = (float*)d_ws;                    // fp32 residual stream [NE]
    float* Wp = W0 + NE;                         // fp32 proj / ffn out  [NE]
    unsigned short* Xb = (unsigned short*)(Wp + NE);  // bf16 x_cur [NE]
    unsigned short* Qb = Xb + NE;
    unsigned short* Kbuf = Qb + NE;
    unsigned short* Vb = Kbuf + NE;
    unsigned short* Ob = Vb + NE;
    unsigned short* Hb = Qb;                     // bf16 hidden [NTOK*DFF] overlays Qb..Ob
    unsigned short* WT = Ob + NE;                // bf16 transposed weights
    unsigned short* sqT = WT;
    unsigned short* skT = sqT + EE;
    unsigned short* svT = skT + EE;
    unsigned short* soT = svT + EE;
    unsigned short* tqT = soT + EE;
    unsigned short* tkT = tqT + EE;
    unsigned short* tvT = tkT + EE;
    unsigned short* toT = tvT + EE;
    unsigned short* w1T = toT + EE;              // [DFF][E]
    unsigned short* w2T = w1T + (size_t)cDFF * cE;  // [E][DFF]

    const dim3 blk(256);
    const dim3 gLN(NTOK);
    const dim3 gProj(cE / 128, NTOK / 128);      // (6, 128)
    const dim3 gFF1(cDFF / 128, NTOK / 128);     // (24, 128)

    // ---- prep: cast x, transpose+cast all weights to bf16 [N][K] ----
    cast_bf16_kernel<<<dim3(2048), blk, 0, stream>>>(x, Xb, (int)(NE / 4));
    {
        TP8 p;
        p.src[0] = sq_w; p.dst[0] = sqT;
        p.src[1] = sk_w; p.dst[1] = skT;
        p.src[2] = sv_w; p.dst[2] = svT;
        p.src[3] = so_w; p.dst[3] = soT;
        p.src[4] = tq_w; p.dst[4] = tqT;
        p.src[5] = tk_w; p.dst[5] = tkT;
        p.src[6] = tv_w; p.dst[6] = tvT;
        p.src[7] = to_w; p.dst[7] = toT;
        transpose_cast8_kernel<<<dim3(cE / 32, cE / 32, 8), blk, 0, stream>>>(p);
    }
    transpose_cast_kernel<<<dim3(cDFF / 32, cE / 32), blk, 0, stream>>>(w1, w1T, cE, cDFF);
    transpose_cast_kernel<<<dim3(cE / 32, cDFF / 32), blk, 0, stream>>>(w2, w2T, cDFF, cE);

    // ---- Spatial attention block ----
    gemm_mfma_kernel<1,0><<<gProj, blk, 0, stream>>>(Xb, sqT, sq_b, Qb, NTOK, cE, cE);
    gemm_mfma_kernel<1,0><<<gProj, blk, 0, stream>>>(Xb, skT, sk_b, Kbuf, NTOK, cE, cE);
    gemm_mfma_kernel<1,0><<<gProj, blk, 0, stream>>>(Xb, svT, sv_b, Vb, NTOK, cE, cE);
    spatial_attn_mfma_kernel<<<dim3(cB * cT * cH), blk, 0, stream>>>(Qb, Kbuf, Vb, Ob);
    gemm_mfma_kernel<0,0><<<gProj, blk, 0, stream>>>(Ob, soT, so_b, Wp, NTOK, cE, cE);
    residual_ln_kernel<<<gLN, blk, 0, stream>>>(x, Wp, sg, sb, W0, Xb);

    // ---- Temporal attention block ----
    gemm_mfma_kernel<1,0><<<gProj, blk, 0, stream>>>(Xb, tqT, tq_b, Qb, NTOK, cE, cE);
    gemm_mfma_kernel<1,0><<<gProj, blk, 0, stream>>>(Xb, tkT, tk_b, Kbuf, NTOK, cE, cE);
    gemm_mfma_kernel<1,0><<<gProj, blk, 0, stream>>>(Xb, tvT, tv_b, Vb, NTOK, cE, cE);
    temporal_attn_kernel<<<dim3(cB * cP * 2), dim3(128), 0, stream>>>(Qb, Kbuf, Vb, Ob);
    gemm_mfma_kernel<0,0><<<gProj, blk, 0, stream>>>(Ob, toT, to_b, Wp, NTOK, cE, cE);
    residual_ln_kernel<<<gLN, blk, 0, stream>>>(W0, Wp, tg, tb, W0, Xb);

    // ---- FFN ----
    gemm_mfma_kernel<1,1><<<gFF1, blk, 0, stream>>>(Xb, w1T, b1, Hb, NTOK, cDFF, cE);
    gemm_mfma_kernel<0,0><<<gProj, blk, 0, stream>>>(Hb, w2T, b2, Wp, NTOK, cE, cDFF);
    residual_ln_kernel<<<gLN, blk, 0, stream>>>(W0, Wp, g, bb, (float*)d_out, nullptr);
}

// Round 6
// 755.491 us; speedup vs baseline: 1.6677x; 1.0401x over previous
//
#include <hip/hip_runtime.h>
#include <math.h>

// Problem constants
constexpr int cB   = 4;
constexpr int cT   = 16;
constexpr int cP   = 256;
constexpr int cE   = 768;
constexpr int cH   = 12;
constexpr int cD   = 64;
constexpr int cDFF = 3072;
constexpr int NTOK = cB * cT * cP;        // 16384
constexpr float cSCALE = 0.125f;          // 64^-0.5
constexpr float cEPS = 1e-5f;

typedef __attribute__((ext_vector_type(8))) short short8;
typedef __attribute__((ext_vector_type(4))) float f32x4;
typedef __attribute__((ext_vector_type(8))) unsigned short u16x8;
typedef __attribute__((ext_vector_type(4))) unsigned short u16x4;

#define AS1 __attribute__((address_space(1)))
#define AS3 __attribute__((address_space(3)))

__device__ inline float b2f(unsigned short u) {
    union { unsigned int i; float f; } c; c.i = ((unsigned int)u) << 16; return c.f;
}
__device__ inline unsigned short f2b(float f) {
    union { float f; unsigned int i; } c; c.f = f;
    unsigned int i = c.i;
    unsigned int r = i + 0x7FFFu + ((i >> 16) & 1u);   // RNE
    return (unsigned short)(r >> 16);
}

__device__ inline void gload16(const unsigned short* g, short* l) {
    __builtin_amdgcn_global_load_lds((AS1 const void*)g, (AS3 void*)l, 16, 0, 0);
}

// Stage a 128x64 bf16 half-tile: wave w loads rows [w*16, w*16+16), 2 loads of
// 8 rows each; lane l -> row w*16+j*8+(l>>3), 16B slot l&7. LDS dest is linear
// (wave-uniform base + lane*16); global source column is inverse-swizzled so a
// swizzled ds_read_b128 (byte ^= (row&7)<<4) retrieves k-major fragments
// conflict-free (both-sides-or-neither rule).
__device__ inline void stage_half(const unsigned short* Xg, int K,
                                  short* ldsbase, int w, int l) {
    #pragma unroll
    for (int j = 0; j < 2; ++j) {
        const int r = w * 16 + j * 8 + (l >> 3);
        const int sl = l & 7;
        gload16(Xg + (size_t)r * K + ((sl ^ (r & 7)) << 3),
                ldsbase + r * 64 + (sl << 3));
    }
}

// ---------------------------------------------------------------------------
// 256x256 8-phase MFMA GEMM: C[M,N] = A[M,K](bf16) @ BT[N,K]^T(bf16) + bias
// BK=64, 2 K-tiles per iteration, 512 threads (8 waves 2Mx4N), 128 KiB LDS
// double-buffer, raw s_barrier + counted waits (vmcnt(0) only at phases 4/8,
// each load covered by 1-4 MFMA phases), T2 XOR swizzle, T5 setprio,
// T1 bijective XCD swizzle (grids are %8==0).
// SPLIT3: N=2304 QKV fusion -> epilogue routes each 256-col block to C0/C1/C2.
// OUTB: 1 -> bf16 out, 0 -> fp32 out.  ACT: 1 -> exact GELU.
// ---------------------------------------------------------------------------
template<int OUTB, int ACT, int SPLIT3>
__global__ __launch_bounds__(512, 2) void gemm256_kernel(
    const unsigned short* __restrict__ A,   // [M][K] bf16
    const unsigned short* __restrict__ BT,  // [N][K] bf16
    const float* __restrict__ bias0, const float* __restrict__ bias1,
    const float* __restrict__ bias2,
    void* __restrict__ C0, void* __restrict__ C1, void* __restrict__ C2,
    int M, int N, int K, int nbn)
{
    __shared__ short As[2 * 256 * 64];   // 64 KiB: 2 buffers x [256][64]
    __shared__ short Bs[2 * 256 * 64];   // 64 KiB

    const int tid = threadIdx.x;
    const int w = tid >> 6, l = tid & 63;
    const int l15 = l & 15, l16 = l >> 4;
    const int wm = w >> 2, wn = w & 3;

    // bijective XCD swizzle (nwg % 8 == 0 for all our grids)
    const int nwg = gridDim.x;
    const int wg = (blockIdx.x & 7) * (nwg >> 3) + (blockIdx.x >> 3);
    const int bm = wg / nbn, bn = wg % nbn;
    const int m0 = bm * 256, n0 = bn * 256;

    const unsigned short* pA0 = A + (size_t)m0 * K;
    const unsigned short* pA1 = A + (size_t)(m0 + 128) * K;
    const unsigned short* pB0 = BT + (size_t)n0 * K;
    const unsigned short* pB1 = BT + (size_t)(n0 + 128) * K;

    f32x4 acc[8][4];
    #pragma unroll
    for (int i = 0; i < 8; ++i)
        #pragma unroll
        for (int j = 0; j < 4; ++j)
            #pragma unroll
            for (int r = 0; r < 4; ++r) acc[i][j][r] = 0.f;

    // prologue: stage K-tile 0 into buffer 0, full drain once
    stage_half(pA0, K, As, w, l);
    stage_half(pA1, K, As + 8192, w, l);
    stage_half(pB0, K, Bs, w, l);
    stage_half(pB1, K, Bs + 8192, w, l);
    asm volatile("s_waitcnt vmcnt(0)" ::: "memory");
    __builtin_amdgcn_s_barrier();

    short8 bF[4][2];
    const int niter = K >> 7;     // 2 K-tiles (BK=64) per iteration
    int k0 = 0;
    for (int it = 0; it < niter; ++it) {
        const int kb = k0 + 64;                                 // -> buf1
        const int kc = (k0 + 128 < K) ? (k0 + 128) : 0;         // -> buf0
        #pragma unroll
        for (int p = 0; p < 8; ++p) {
            const int c = p >> 2;   // buffer being computed
            const int q = p & 3;    // quadrant (m-frags 2q, 2q+1)

            // ---- ds_read fragments from buf c (swizzled) ----
            short8 aF[2][2];
            if (q == 0) {
                #pragma unroll
                for (int nf = 0; nf < 4; ++nf) {
                    const int rb = wn * 64 + nf * 16 + l15;
                    const char* pb = (const char*)Bs + c * 32768 + rb * 128;
                    const int sw = (rb & 7) << 4;
                    bF[nf][0] = *(const short8*)(pb + ((l16 * 16) ^ sw));
                    bF[nf][1] = *(const short8*)(pb + ((64 + l16 * 16) ^ sw));
                }
            }
            #pragma unroll
            for (int mm = 0; mm < 2; ++mm) {
                const int ra = wm * 128 + (q * 2 + mm) * 16 + l15;
                const char* pa = (const char*)As + c * 32768 + ra * 128;
                const int sw = (ra & 7) << 4;
                aF[mm][0] = *(const short8*)(pa + ((l16 * 16) ^ sw));
                aF[mm][1] = *(const short8*)(pa + ((64 + l16 * 16) ^ sw));
            }

            // ---- stage one half-tile into buf c^1 (freed last phase-group) --
            {
                const int koff = (p < 4) ? kb : kc;
                short* dst = ((q < 2) ? As : Bs) + ((c ^ 1) * 16384) + ((q & 1) * 8192);
                const unsigned short* src =
                    (q == 0 ? pA0 : q == 1 ? pA1 : q == 2 ? pB0 : pB1) + koff;
                stage_half(src, K, dst, w, l);
            }

            __builtin_amdgcn_s_barrier();
            asm volatile("s_waitcnt lgkmcnt(0)" ::: "memory");
            __builtin_amdgcn_sched_barrier(0);
            __builtin_amdgcn_s_setprio(1);
            #pragma unroll
            for (int kk = 0; kk < 2; ++kk)
                #pragma unroll
                for (int nf = 0; nf < 4; ++nf)
                    #pragma unroll
                    for (int mm = 0; mm < 2; ++mm)
                        acc[q * 2 + mm][nf] = __builtin_amdgcn_mfma_f32_16x16x32_bf16(
                            aF[mm][kk], bF[nf][kk], acc[q * 2 + mm][nf], 0, 0, 0);
            __builtin_amdgcn_s_setprio(0);
            __builtin_amdgcn_sched_barrier(0);
            if (q == 3)
                asm volatile("s_waitcnt vmcnt(0)" ::: "memory");
            __builtin_amdgcn_s_barrier();
        }
        k0 += 128;
    }

    // ---- epilogue: C/D layout col = lane&15, row = (lane>>4)*4 + reg ----
    #pragma unroll
    for (int mf = 0; mf < 8; ++mf) {
        #pragma unroll
        for (int nf = 0; nf < 4; ++nf) {
            const int ng = n0 + wn * 64 + nf * 16 + l15;
            int nl = ng;
            const float* bp = bias0;
            void* Cp = C0;
            int Nout = N;
            if (SPLIT3) {
                const int which = ng / 768;      // uniform per block (768=3*256)
                nl = ng - which * 768;
                bp = (which == 0) ? bias0 : (which == 1) ? bias1 : bias2;
                Cp = (which == 0) ? C0 : (which == 1) ? C1 : C2;
                Nout = 768;
            }
            const float bs = bp[nl];
            #pragma unroll
            for (int r = 0; r < 4; ++r) {
                const int row = m0 + wm * 128 + mf * 16 + l16 * 4 + r;
                float v = acc[mf][nf][r] + bs;
                if (ACT) v = 0.5f * v * (1.f + erff(v * 0.70710678118654752f));
                if (OUTB) ((unsigned short*)Cp)[(size_t)row * Nout + nl] = f2b(v);
                else      ((float*)Cp)[(size_t)row * Nout + nl] = v;
            }
        }
    }
}

// ---------------------------------------------------------------------------
// weight prep: W[K][N] fp32 -> WT[N][K] bf16  (32x32 LDS tile transpose)
// ---------------------------------------------------------------------------
__global__ __launch_bounds__(256) void transpose_cast_kernel(
    const float* __restrict__ W, unsigned short* __restrict__ WT,
    int K, int N)
{
    __shared__ float t[32][33];
    const int k0 = blockIdx.y * 32;
    const int n0 = blockIdx.x * 32;
    const int tx = threadIdx.x & 31;
    const int ty4 = (threadIdx.x >> 5) << 2;
    #pragma unroll
    for (int i = 0; i < 4; ++i)
        t[ty4 + i][tx] = W[(size_t)(k0 + ty4 + i) * N + n0 + tx];
    __syncthreads();
    #pragma unroll
    for (int i = 0; i < 4; ++i)
        WT[(size_t)(n0 + ty4 + i) * K + k0 + tx] = f2b(t[tx][ty4 + i]);
}

// fused prep for the 8 E x E attention weights (grid.z selects weight)
struct TP8 { const float* src[8]; unsigned short* dst[8]; };
__global__ __launch_bounds__(256) void transpose_cast8_kernel(TP8 p)
{
    __shared__ float t[32][33];
    const int z = blockIdx.z;
    const float* W = p.src[z];
    unsigned short* WT = p.dst[z];
    const int k0 = blockIdx.y * 32;
    const int n0 = blockIdx.x * 32;
    const int tx = threadIdx.x & 31;
    const int ty4 = (threadIdx.x >> 5) << 2;
    #pragma unroll
    for (int i = 0; i < 4; ++i)
        t[ty4 + i][tx] = W[(size_t)(k0 + ty4 + i) * cE + n0 + tx];
    __syncthreads();
    #pragma unroll
    for (int i = 0; i < 4; ++i)
        WT[(size_t)(n0 + ty4 + i) * cE + k0 + tx] = f2b(t[tx][ty4 + i]);
}

// fp32 -> bf16 elementwise (n multiple of 4)
__global__ __launch_bounds__(256) void cast_bf16_kernel(
    const float* __restrict__ in, unsigned short* __restrict__ out, int n4)
{
    for (int i = blockIdx.x * blockDim.x + threadIdx.x; i < n4;
         i += gridDim.x * blockDim.x) {
        float4 v = ((const float4*)in)[i];
        u16x4 o;
        o[0] = f2b(v.x); o[1] = f2b(v.y); o[2] = f2b(v.z); o[3] = f2b(v.w);
        *(u16x4*)(out + (size_t)i * 4) = o;
    }
}

// ---------------------------------------------------------------------------
// residual + layernorm: out = LN(X + R) * gamma + beta  (fp32), optional bf16 copy
// ---------------------------------------------------------------------------
__global__ __launch_bounds__(256) void residual_ln_kernel(
    const float* __restrict__ X, const float* __restrict__ R,
    const float* __restrict__ gamma, const float* __restrict__ beta,
    float* __restrict__ out, unsigned short* __restrict__ outb)
{
    const int row = blockIdx.x;
    const size_t off = (size_t)row * cE;
    const int tid = threadIdx.x;

    float v[3];
    float s = 0.f, ss = 0.f;
    #pragma unroll
    for (int i = 0; i < 3; ++i) {
        const int e = tid + i * 256;
        const float t = X[off + e] + R[off + e];
        v[i] = t; s += t; ss += t * t;
    }
    #pragma unroll
    for (int o = 32; o > 0; o >>= 1) {
        s  += __shfl_down(s, o);
        ss += __shfl_down(ss, o);
    }
    __shared__ float rs[4], rss[4];
    const int wid = tid >> 6;
    if ((tid & 63) == 0) { rs[wid] = s; rss[wid] = ss; }
    __syncthreads();
    s  = rs[0] + rs[1] + rs[2] + rs[3];
    ss = rss[0] + rss[1] + rss[2] + rss[3];

    const float mean = s * (1.f / cE);
    const float var  = ss * (1.f / cE) - mean * mean;
    const float inv  = rsqrtf(var + cEPS);
    #pragma unroll
    for (int i = 0; i < 3; ++i) {
        const int e = tid + i * 256;
        const float r = (v[i] - mean) * inv * gamma[e] + beta[e];
        out[off + e] = r;
        if (outb) outb[off + e] = f2b(r);
    }
}

// ---------------------------------------------------------------------------
// Spatial attention, MFMA flash version (unchanged from round 4; verified).
// ---------------------------------------------------------------------------
__global__ __launch_bounds__(256) void spatial_attn_mfma_kernel(
    const unsigned short* __restrict__ Q, const unsigned short* __restrict__ K,
    const unsigned short* __restrict__ V, unsigned short* __restrict__ O)
{
    __shared__ short Ks[64 * 64];      // [j][d] swizzled, row 128B
    __shared__ short Vt[64 * 64];      // [d][j] swizzled
    __shared__ short Ps[4][64 * 64];   // per-wave [q][j] swizzled

    const int bid = blockIdx.x;        // b*T*H + t*H + h
    const int h  = bid % cH;
    const int bt = bid / cH;
    const size_t base = (size_t)bt * cP * cE + h * cD;

    const int tid = threadIdx.x;
    const int w = tid >> 6, l = tid & 63;
    const int l15 = l & 15, l16 = l >> 4;

    short8 qf[4][2];
    #pragma unroll
    for (int mf = 0; mf < 4; ++mf)
        #pragma unroll
        for (int kf = 0; kf < 2; ++kf)
            qf[mf][kf] = *(const short8*)(
                Q + base + (size_t)(w * 64 + mf * 16 + l15) * cE + kf * 32 + l16 * 8);

    f32x4 o[4][4];
    float mrun[4][4], lrun[4][4];
    #pragma unroll
    for (int mf = 0; mf < 4; ++mf)
        #pragma unroll
        for (int j = 0; j < 4; ++j) {
            #pragma unroll
            for (int r = 0; r < 4; ++r) o[mf][j][r] = 0.f;
            mrun[mf][j] = -INFINITY; lrun[mf][j] = 0.f;
        }

    const int krow = w * 8 + (l >> 3);
    const int kc16 = l & 7;
    const int vj  = tid & 31;
    const int vd0 = (tid >> 5) * 8;

    for (int c0 = 0; c0 < cP; c0 += 64) {
        __syncthreads();
        #pragma unroll
        for (int p = 0; p < 2; ++p) {
            const int row = p * 32 + krow;
            gload16(K + base + (size_t)(c0 + row) * cE + ((kc16 ^ (row & 7)) << 3),
                    Ks + row * 64 + kc16 * 8);
        }
        #pragma unroll
        for (int p = 0; p < 2; ++p) {
            const int j = p * 32 + vj;
            short8 vv = *(const short8*)(V + base + (size_t)(c0 + j) * cE + vd0);
            char* vb = (char*)Vt;
            #pragma unroll
            for (int e = 0; e < 8; ++e) {
                const int row = vd0 + e;
                *(short*)(vb + row * 128 + ((2 * j) ^ ((row & 7) << 4))) = vv[e];
            }
        }
        __syncthreads();

        f32x4 s[4][4];
        #pragma unroll
        for (int mf = 0; mf < 4; ++mf)
            #pragma unroll
            for (int nf = 0; nf < 4; ++nf)
                #pragma unroll
                for (int r = 0; r < 4; ++r) s[mf][nf][r] = 0.f;

        #pragma unroll
        for (int nf = 0; nf < 4; ++nf) {
            const int row = nf * 16 + l15;
            const char* kb = (const char*)Ks + row * 128;
            const int sw = (row & 7) << 4;
            short8 k0 = *(const short8*)(kb + ((l16 * 16) ^ sw));
            short8 k1 = *(const short8*)(kb + ((64 + l16 * 16) ^ sw));
            #pragma unroll
            for (int mf = 0; mf < 4; ++mf) {
                s[mf][nf] = __builtin_amdgcn_mfma_f32_16x16x32_bf16(qf[mf][0], k0, s[mf][nf], 0, 0, 0);
                s[mf][nf] = __builtin_amdgcn_mfma_f32_16x16x32_bf16(qf[mf][1], k1, s[mf][nf], 0, 0, 0);
            }
        }

        #pragma unroll
        for (int mf = 0; mf < 4; ++mf)
            #pragma unroll
            for (int nf = 0; nf < 4; ++nf)
                #pragma unroll
                for (int r = 0; r < 4; ++r) s[mf][nf][r] *= cSCALE;

        #pragma unroll
        for (int mf = 0; mf < 4; ++mf) {
            #pragma unroll
            for (int r = 0; r < 4; ++r) {
                float rv = fmaxf(fmaxf(s[mf][0][r], s[mf][1][r]),
                                 fmaxf(s[mf][2][r], s[mf][3][r]));
                rv = fmaxf(rv, __shfl_xor(rv, 1));
                rv = fmaxf(rv, __shfl_xor(rv, 2));
                rv = fmaxf(rv, __shfl_xor(rv, 4));
                rv = fmaxf(rv, __shfl_xor(rv, 8));
                const float mn = fmaxf(mrun[mf][r], rv);
                const float al = __expf(mrun[mf][r] - mn);
                mrun[mf][r] = mn;
                float ps = 0.f;
                #pragma unroll
                for (int nf = 0; nf < 4; ++nf) {
                    const float pe = __expf(s[mf][nf][r] - mn);
                    s[mf][nf][r] = pe;
                    ps += pe;
                }
                ps += __shfl_xor(ps, 1);
                ps += __shfl_xor(ps, 2);
                ps += __shfl_xor(ps, 4);
                ps += __shfl_xor(ps, 8);
                lrun[mf][r] = lrun[mf][r] * al + ps;
                #pragma unroll
                for (int df = 0; df < 4; ++df) o[mf][df][r] *= al;
            }
        }

        char* pw = (char*)&Ps[w][0];
        #pragma unroll
        for (int mf = 0; mf < 4; ++mf)
            #pragma unroll
            for (int nf = 0; nf < 4; ++nf)
                #pragma unroll
                for (int r = 0; r < 4; ++r) {
                    const int row = mf * 16 + l16 * 4 + r;
                    *(short*)(pw + row * 128 + (((nf * 16 + l15) * 2) ^ ((row & 7) << 4))) =
                        (short)f2b(s[mf][nf][r]);
                }

        short8 pa[4][2];
        #pragma unroll
        for (int mf = 0; mf < 4; ++mf) {
            const int prow = mf * 16 + l15;
            const char* pb = (const char*)&Ps[w][0] + prow * 128;
            const int sw = (prow & 7) << 4;
            pa[mf][0] = *(const short8*)(pb + ((l16 * 16) ^ sw));
            pa[mf][1] = *(const short8*)(pb + ((64 + l16 * 16) ^ sw));
        }
        #pragma unroll
        for (int df = 0; df < 4; ++df) {
            const int vrow = df * 16 + l15;
            const char* vbb = (const char*)Vt + vrow * 128;
            const int sw = (vrow & 7) << 4;
            short8 v0 = *(const short8*)(vbb + ((l16 * 16) ^ sw));
            short8 v1 = *(const short8*)(vbb + ((64 + l16 * 16) ^ sw));
            #pragma unroll
            for (int mf = 0; mf < 4; ++mf) {
                o[mf][df] = __builtin_amdgcn_mfma_f32_16x16x32_bf16(pa[mf][0], v0, o[mf][df], 0, 0, 0);
                o[mf][df] = __builtin_amdgcn_mfma_f32_16x16x32_bf16(pa[mf][1], v1, o[mf][df], 0, 0, 0);
            }
        }
    }

    #pragma unroll
    for (int mf = 0; mf < 4; ++mf)
        #pragma unroll
        for (int r = 0; r < 4; ++r) {
            const float inv = 1.f / lrun[mf][r];
            const size_t rowoff = base + (size_t)(w * 64 + mf * 16 + l16 * 4 + r) * cE;
            #pragma unroll
            for (int df = 0; df < 4; ++df)
                O[rowoff + df * 16 + l15] = f2b(o[mf][df][r] * inv);
        }
}

// ---------------------------------------------------------------------------
// Temporal causal attention (bf16 I/O): per (b,p,head-group of 6). T=16.
// ---------------------------------------------------------------------------
__global__ __launch_bounds__(128) void temporal_attn_kernel(
    const unsigned short* __restrict__ Q, const unsigned short* __restrict__ Kb,
    const unsigned short* __restrict__ V, unsigned short* __restrict__ O)
{
    const int bid = blockIdx.x;          // (b*P + p)*2 + hg
    const int hg  = bid & 1;
    const int bp  = bid >> 1;
    const int p   = bp % cP;
    const int b   = bp / cP;

    __shared__ float Ks[cT][6][cD + 1];
    __shared__ float Vs[cT][6][cD + 1];

    const size_t framestride = (size_t)cP * cE;
    const size_t base0 = ((size_t)(b * cT) * cP + p) * cE + hg * 384;

    for (int li = threadIdx.x; li < cT * 384; li += 128) {
        const int s = li / 384;
        const int r = li % 384;
        const size_t src = base0 + (size_t)s * framestride + r;
        Ks[s][r / 64][r & 63] = b2f(Kb[src]);
        Vs[s][r / 64][r & 63] = b2f(V[src]);
    }
    __syncthreads();
    if (threadIdx.x >= 96) return;

    const int hh = threadIdx.x >> 4;
    const int t  = threadIdx.x & 15;
    const size_t qoff = ((size_t)(b * cT + t) * cP + p) * cE + hg * 384 + hh * cD;

    float q[cD];
    #pragma unroll
    for (int d = 0; d < cD; d += 8) {
        short8 f = *(const short8*)(Q + qoff + d);
        #pragma unroll
        for (int j = 0; j < 8; ++j) q[d + j] = b2f((unsigned short)f[j]);
    }

    float sc[cT];
    float mx = -INFINITY;
    #pragma unroll
    for (int s = 0; s < cT; ++s) {
        float acc = 0.f;
        #pragma unroll
        for (int d = 0; d < cD; ++d) acc = fmaf(q[d], Ks[s][hh][d], acc);
        sc[s] = (s <= t) ? acc * cSCALE : -INFINITY;
        mx = fmaxf(mx, sc[s]);
    }
    float l = 0.f;
    #pragma unroll
    for (int s = 0; s < cT; ++s) {
        const float e_ = __expf(sc[s] - mx);
        sc[s] = e_;
        l += e_;
    }
    float o[cD];
    #pragma unroll
    for (int d = 0; d < cD; ++d) o[d] = 0.f;
    #pragma unroll
    for (int s = 0; s < cT; ++s) {
        const float pj = sc[s];
        #pragma unroll
        for (int d = 0; d < cD; ++d) o[d] = fmaf(pj, Vs[s][hh][d], o[d]);
    }
    const float invl = 1.f / l;
    unsigned short* op = O + qoff;
    #pragma unroll
    for (int d = 0; d < cD; d += 8) {
        u16x8 f;
        #pragma unroll
        for (int j = 0; j < 8; ++j) f[j] = f2b(o[d + j] * invl);
        *(u16x8*)(op + d) = f;
    }
}

// ---------------------------------------------------------------------------
extern "C" void kernel_launch(void* const* d_in, const int* in_sizes, int n_in,
                              void* d_out, int out_size, void* d_ws, size_t ws_size,
                              hipStream_t stream)
{
    const float* x    = (const float*)d_in[0];
    const float* sq_w = (const float*)d_in[1];
    const float* sk_w = (const float*)d_in[2];
    const float* sv_w = (const float*)d_in[3];
    const float* so_w = (const float*)d_in[4];
    const float* sq_b = (const float*)d_in[5];
    const float* sk_b = (const float*)d_in[6];
    const float* sv_b = (const float*)d_in[7];
    const float* so_b = (const float*)d_in[8];
    const float* sg   = (const float*)d_in[9];
    const float* sb   = (const float*)d_in[10];
    const float* tq_w = (const float*)d_in[11];
    const float* tk_w = (const float*)d_in[12];
    const float* tv_w = (const float*)d_in[13];
    const float* to_w = (const float*)d_in[14];
    const float* tq_b = (const float*)d_in[15];
    const float* tk_b = (const float*)d_in[16];
    const float* tv_b = (const float*)d_in[17];
    const float* to_b = (const float*)d_in[18];
    const float* tg   = (const float*)d_in[19];
    const float* tb   = (const float*)d_in[20];
    const float* w1   = (const float*)d_in[21];
    const float* b1   = (const float*)d_in[22];
    const float* w2   = (const float*)d_in[23];
    const float* b2   = (const float*)d_in[24];
    const float* g    = (const float*)d_in[25];
    const float* bb   = (const float*)d_in[26];

    const size_t NE = (size_t)NTOK * cE;   // 12.58M elements
    const size_t EE = (size_t)cE * cE;     // 589824

    // workspace layout (~245 MB)
    float* W0 = (float*)d_ws;                    // fp32 residual stream [NE]
    float* Wp = W0 + NE;                         // fp32 proj / ffn out  [NE]
    unsigned short* Xb = (unsigned short*)(Wp + NE);  // bf16 x_cur [NE]
    unsigned short* Qb = Xb + NE;
    unsigned short* Kbuf = Qb + NE;
    unsigned short* Vb = Kbuf + NE;
    unsigned short* Ob = Vb + NE;
    unsigned short* Hb = Qb;                     // bf16 hidden [NTOK*DFF] overlays Qb..Ob
    unsigned short* WT = Ob + NE;                // bf16 transposed weights
    unsigned short* sqT = WT;                    // [sq;sk;sv] contiguous -> QKV fused B
    unsigned short* skT = sqT + EE;
    unsigned short* svT = skT + EE;
    unsigned short* soT = svT + EE;
    unsigned short* tqT = soT + EE;              // [tq;tk;tv] contiguous
    unsigned short* tkT = tqT + EE;
    unsigned short* tvT = tkT + EE;
    unsigned short* toT = tvT + EE;
    unsigned short* w1T = toT + EE;              // [DFF][E]
    unsigned short* w2T = w1T + (size_t)cDFF * cE;  // [E][DFF]

    const dim3 blk(256);
    const dim3 blk512(512);
    const dim3 gLN(NTOK);
    const dim3 gQKV(576);        // (2304/256) * (16384/256)
    const dim3 gOUT(192);        // (768/256)  * 64
    const dim3 gFF1(768);        // (3072/256) * 64

    // ---- prep: cast x, transpose+cast all weights to bf16 [N][K] ----
    cast_bf16_kernel<<<dim3(2048), blk, 0, stream>>>(x, Xb, (int)(NE / 4));
    {
        TP8 p;
        p.src[0] = sq_w; p.dst[0] = sqT;
        p.src[1] = sk_w; p.dst[1] = skT;
        p.src[2] = sv_w; p.dst[2] = svT;
        p.src[3] = so_w; p.dst[3] = soT;
        p.src[4] = tq_w; p.dst[4] = tqT;
        p.src[5] = tk_w; p.dst[5] = tkT;
        p.src[6] = tv_w; p.dst[6] = tvT;
        p.src[7] = to_w; p.dst[7] = toT;
        transpose_cast8_kernel<<<dim3(cE / 32, cE / 32, 8), blk, 0, stream>>>(p);
    }
    transpose_cast_kernel<<<dim3(cDFF / 32, cE / 32), blk, 0, stream>>>(w1, w1T, cE, cDFF);
    transpose_cast_kernel<<<dim3(cE / 32, cDFF / 32), blk, 0, stream>>>(w2, w2T, cDFF, cE);

    // ---- Spatial attention block ----
    gemm256_kernel<1,0,1><<<gQKV, blk512, 0, stream>>>(
        Xb, sqT, sq_b, sk_b, sv_b, Qb, Kbuf, Vb, NTOK, 2304, cE, 9);
    spatial_attn_mfma_kernel<<<dim3(cB * cT * cH), blk, 0, stream>>>(Qb, Kbuf, Vb, Ob);
    gemm256_kernel<0,0,0><<<gOUT, blk512, 0, stream>>>(
        Ob, soT, so_b, nullptr, nullptr, Wp, nullptr, nullptr, NTOK, cE, cE, 3);
    residual_ln_kernel<<<gLN, blk, 0, stream>>>(x, Wp, sg, sb, W0, Xb);

    // ---- Temporal attention block ----
    gemm256_kernel<1,0,1><<<gQKV, blk512, 0, stream>>>(
        Xb, tqT, tq_b, tk_b, tv_b, Qb, Kbuf, Vb, NTOK, 2304, cE, 9);
    temporal_attn_kernel<<<dim3(cB * cP * 2), dim3(128), 0, stream>>>(Qb, Kbuf, Vb, Ob);
    gemm256_kernel<0,0,0><<<gOUT, blk512, 0, stream>>>(
        Ob, toT, to_b, nullptr, nullptr, Wp, nullptr, nullptr, NTOK, cE, cE, 3);
    residual_ln_kernel<<<gLN, blk, 0, stream>>>(W0, Wp, tg, tb, W0, Xb);

    // ---- FFN ----
    gemm256_kernel<1,1,0><<<gFF1, blk512, 0, stream>>>(
        Xb, w1T, b1, nullptr, nullptr, Hb, nullptr, nullptr, NTOK, cDFF, cE, 12);
    gemm256_kernel<0,0,0><<<gOUT, blk512, 0, stream>>>(
        Hb, w2T, b2, nullptr, nullptr, Wp, nullptr, nullptr, NTOK, cE, cDFF, 3);
    residual_ln_kernel<<<gLN, blk, 0, stream>>>(W0, Wp, g, bb, (float*)d_out, nullptr);
}

// Round 7
// 710.779 us; speedup vs baseline: 1.7726x; 1.0629x over previous
//
#include <hip/hip_runtime.h>
#include <math.h>

// Problem constants
constexpr int cB   = 4;
constexpr int cT   = 16;
constexpr int cP   = 256;
constexpr int cE   = 768;
constexpr int cH   = 12;
constexpr int cD   = 64;
constexpr int cDFF = 3072;
constexpr int NTOK = cB * cT * cP;        // 16384
constexpr float cSCALE = 0.125f;          // 64^-0.5
constexpr float cEPS = 1e-5f;

typedef __attribute__((ext_vector_type(8))) short short8;
typedef __attribute__((ext_vector_type(4))) float f32x4;
typedef __attribute__((ext_vector_type(8))) unsigned short u16x8;
typedef __attribute__((ext_vector_type(4))) unsigned short u16x4;

#define AS1 __attribute__((address_space(1)))
#define AS3 __attribute__((address_space(3)))

__device__ inline float b2f(unsigned short u) {
    union { unsigned int i; float f; } c; c.i = ((unsigned int)u) << 16; return c.f;
}
__device__ inline unsigned short f2b(float f) {
    union { float f; unsigned int i; } c; c.f = f;
    unsigned int i = c.i;
    unsigned int r = i + 0x7FFFu + ((i >> 16) & 1u);   // RNE
    return (unsigned short)(r >> 16);
}

__device__ inline void gload16(const unsigned short* g, short* l) {
    __builtin_amdgcn_global_load_lds((AS1 const void*)g, (AS3 void*)l, 16, 0, 0);
}

// ---------------------------------------------------------------------------
// 256x128 3-deep-pipelined MFMA GEMM: C = A[M,K](bf16) @ BT[N,K]^T(bf16) + bias
// BK=64, 512 threads (8 waves, 4M x 2N, 64x64 out per wave), 3 LDS buffers
// (A 32KB + B 16KB each, 144 KiB total). Per K-tile: 16 ds_read_b128 (kk0/kk1
// groups order-pinned), stage tile t+2 (6 gload_lds), lgkmcnt(8) -> MFMA kk0,
// lgkmcnt(0) -> MFMA kk1, vmcnt(6) (t+1 retired, t+2 in flight), 1 s_barrier.
// T2 both-sides swizzle (byte ^= (row&7)<<4, inverse-swizzled global source).
// T1 bijective XCD swizzle (grids %8==0). T5 setprio around MFMA clusters.
// SPLIT3: N=2304 QKV fusion (128 | 768, so col-block uniform).
// OUTB: 1 -> bf16 out, 0 -> fp32 out.  ACT: 1 -> exact GELU.
// ---------------------------------------------------------------------------
template<int OUTB, int ACT, int SPLIT3>
__global__ __launch_bounds__(512, 2) void gemm256_kernel(
    const unsigned short* __restrict__ A,   // [M][K] bf16
    const unsigned short* __restrict__ BT,  // [N][K] bf16
    const float* __restrict__ bias0, const float* __restrict__ bias1,
    const float* __restrict__ bias2,
    void* __restrict__ C0, void* __restrict__ C1, void* __restrict__ C2,
    int M, int N, int K, int nbn)
{
    __shared__ short LDS[3 * 24576];   // 144 KiB: 3 x (A[256][64] + B[128][64])

    const int tid = threadIdx.x;
    const int w = tid >> 6, l = tid & 63;
    const int l15 = l & 15, l16 = l >> 4;
    const int wm = w >> 1, wn = w & 1;      // 4 M-waves x 2 N-waves
    const int srow = l >> 3;                // staging: row-in-group 0..7
    const int sslot = l & 7;                // staging: 16B slot 0..7

    // bijective XCD swizzle (nwg % 8 == 0 for all our grids)
    const int nwg = gridDim.x;
    const int wg = (blockIdx.x & 7) * (nwg >> 3) + (blockIdx.x >> 3);
    const int bm = wg / nbn, bn = wg % nbn;
    const int m0 = bm * 256, n0 = bn * 128;

    const unsigned short* pA = A + (size_t)m0 * K;
    const unsigned short* pB = BT + (size_t)n0 * K;

    f32x4 acc[4][4];
    #pragma unroll
    for (int i = 0; i < 4; ++i)
        #pragma unroll
        for (int j = 0; j < 4; ++j)
            #pragma unroll
            for (int r = 0; r < 4; ++r) acc[i][j][r] = 0.f;

    const int nt = K >> 6;

    // ---- staging: linear LDS dest (lane*16B), inverse-swizzled global col ----
    #define STAGE_A(t_, buf_)                                                   \
        {                                                                       \
            const unsigned short* src_ = pA + (t_) * 64;                        \
            short* dst_ = LDS + (buf_) * 24576;                                 \
            _Pragma("unroll")                                                   \
            for (int j_ = 0; j_ < 4; ++j_) {                                    \
                const int r_ = w * 32 + j_ * 8 + srow;                          \
                gload16(src_ + (size_t)r_ * K + ((sslot ^ (r_ & 7)) << 3),      \
                        dst_ + r_ * 64 + (sslot << 3));                         \
            }                                                                   \
        }
    #define STAGE_B(t_, buf_)                                                   \
        {                                                                       \
            const unsigned short* src_ = pB + (t_) * 64;                        \
            short* dst_ = LDS + (buf_) * 24576 + 16384;                         \
            _Pragma("unroll")                                                   \
            for (int j_ = 0; j_ < 2; ++j_) {                                    \
                const int r_ = w * 8 + j_ * 64 + srow;                          \
                gload16(src_ + (size_t)r_ * K + ((sslot ^ (r_ & 7)) << 3),      \
                        dst_ + r_ * 64 + (sslot << 3));                         \
            }                                                                   \
        }

    // prologue: stage tiles 0 and 1; wait for tile 0 (6 newest stay in flight)
    STAGE_A(0, 0); STAGE_B(0, 0);
    STAGE_A(1, 1); STAGE_B(1, 1);
    asm volatile("s_waitcnt vmcnt(6)" ::: "memory");
    __builtin_amdgcn_s_barrier();

    int buf = 0;
    for (int t = 0; t < nt; ++t) {
        const short* bA = LDS + buf * 24576;
        const short* bB = bA + 16384;

        short8 aF[4][2], bF[4][2];
        // kk0 fragment reads (8 ds_read_b128)
        #pragma unroll
        for (int mm = 0; mm < 4; ++mm) {
            const int ra = wm * 64 + mm * 16 + l15;
            const char* pa = (const char*)bA + ra * 128;
            aF[mm][0] = *(const short8*)(pa + ((l16 * 16) ^ ((ra & 7) << 4)));
        }
        #pragma unroll
        for (int nf = 0; nf < 4; ++nf) {
            const int rb = wn * 64 + nf * 16 + l15;
            const char* pb = (const char*)bB + rb * 128;
            bF[nf][0] = *(const short8*)(pb + ((l16 * 16) ^ ((rb & 7) << 4)));
        }
        __builtin_amdgcn_sched_barrier(0);   // pin kk0-group issue order
        // kk1 fragment reads (8 ds_read_b128)
        #pragma unroll
        for (int mm = 0; mm < 4; ++mm) {
            const int ra = wm * 64 + mm * 16 + l15;
            const char* pa = (const char*)bA + ra * 128;
            aF[mm][1] = *(const short8*)(pa + ((64 + l16 * 16) ^ ((ra & 7) << 4)));
        }
        #pragma unroll
        for (int nf = 0; nf < 4; ++nf) {
            const int rb = wn * 64 + nf * 16 + l15;
            const char* pb = (const char*)bB + rb * 128;
            bF[nf][1] = *(const short8*)(pb + ((64 + l16 * 16) ^ ((rb & 7) << 4)));
        }

        // stage tile t+2 into the buffer freed at the end of tile t-1
        if (t + 2 < nt) {
            const int b2 = (buf == 0) ? 2 : buf - 1;
            STAGE_A(t + 2, b2); STAGE_B(t + 2, b2);
        }

        asm volatile("s_waitcnt lgkmcnt(8)" ::: "memory");   // kk0 frags ready
        __builtin_amdgcn_sched_barrier(0);
        __builtin_amdgcn_s_setprio(1);
        #pragma unroll
        for (int nf = 0; nf < 4; ++nf)
            #pragma unroll
            for (int mm = 0; mm < 4; ++mm)
                acc[mm][nf] = __builtin_amdgcn_mfma_f32_16x16x32_bf16(
                    aF[mm][0], bF[nf][0], acc[mm][nf], 0, 0, 0);
        __builtin_amdgcn_s_setprio(0);
        asm volatile("s_waitcnt lgkmcnt(0)" ::: "memory");   // kk1 frags ready
        __builtin_amdgcn_sched_barrier(0);
        __builtin_amdgcn_s_setprio(1);
        #pragma unroll
        for (int nf = 0; nf < 4; ++nf)
            #pragma unroll
            for (int mm = 0; mm < 4; ++mm)
                acc[mm][nf] = __builtin_amdgcn_mfma_f32_16x16x32_bf16(
                    aF[mm][1], bF[nf][1], acc[mm][nf], 0, 0, 0);
        __builtin_amdgcn_s_setprio(0);

        if (t + 1 < nt) {
            // retire tile t+1's loads; keep tile t+2's 6 in flight (counted!)
            if (t + 2 < nt)
                asm volatile("s_waitcnt vmcnt(6)" ::: "memory");
            else
                asm volatile("s_waitcnt vmcnt(0)" ::: "memory");
            __builtin_amdgcn_s_barrier();
        }
        buf = (buf == 2) ? 0 : buf + 1;
    }
    #undef STAGE_A
    #undef STAGE_B

    // ---- epilogue: C/D layout col = lane&15, row = (lane>>4)*4 + reg ----
    #pragma unroll
    for (int mf = 0; mf < 4; ++mf) {
        #pragma unroll
        for (int nf = 0; nf < 4; ++nf) {
            const int ng = n0 + wn * 64 + nf * 16 + l15;
            int nl = ng;
            const float* bp = bias0;
            void* Cp = C0;
            int Nout = N;
            if (SPLIT3) {
                const int which = ng / 768;      // uniform per block (128 | 768)
                nl = ng - which * 768;
                bp = (which == 0) ? bias0 : (which == 1) ? bias1 : bias2;
                Cp = (which == 0) ? C0 : (which == 1) ? C1 : C2;
                Nout = 768;
            }
            const float bs = bp[nl];
            #pragma unroll
            for (int r = 0; r < 4; ++r) {
                const int row = m0 + wm * 64 + mf * 16 + l16 * 4 + r;
                float v = acc[mf][nf][r] + bs;
                if (ACT) v = 0.5f * v * (1.f + erff(v * 0.70710678118654752f));
                if (OUTB) ((unsigned short*)Cp)[(size_t)row * Nout + nl] = f2b(v);
                else      ((float*)Cp)[(size_t)row * Nout + nl] = v;
            }
        }
    }
}

// ---------------------------------------------------------------------------
// weight prep: W[K][N] fp32 -> WT[N][K] bf16  (32x32 LDS tile transpose)
// ---------------------------------------------------------------------------
__global__ __launch_bounds__(256) void transpose_cast_kernel(
    const float* __restrict__ W, unsigned short* __restrict__ WT,
    int K, int N)
{
    __shared__ float t[32][33];
    const int k0 = blockIdx.y * 32;
    const int n0 = blockIdx.x * 32;
    const int tx = threadIdx.x & 31;
    const int ty4 = (threadIdx.x >> 5) << 2;
    #pragma unroll
    for (int i = 0; i < 4; ++i)
        t[ty4 + i][tx] = W[(size_t)(k0 + ty4 + i) * N + n0 + tx];
    __syncthreads();
    #pragma unroll
    for (int i = 0; i < 4; ++i)
        WT[(size_t)(n0 + ty4 + i) * K + k0 + tx] = f2b(t[tx][ty4 + i]);
}

// fused prep for the 8 E x E attention weights (grid.z selects weight)
struct TP8 { const float* src[8]; unsigned short* dst[8]; };
__global__ __launch_bounds__(256) void transpose_cast8_kernel(TP8 p)
{
    __shared__ float t[32][33];
    const int z = blockIdx.z;
    const float* W = p.src[z];
    unsigned short* WT = p.dst[z];
    const int k0 = blockIdx.y * 32;
    const int n0 = blockIdx.x * 32;
    const int tx = threadIdx.x & 31;
    const int ty4 = (threadIdx.x >> 5) << 2;
    #pragma unroll
    for (int i = 0; i < 4; ++i)
        t[ty4 + i][tx] = W[(size_t)(k0 + ty4 + i) * cE + n0 + tx];
    __syncthreads();
    #pragma unroll
    for (int i = 0; i < 4; ++i)
        WT[(size_t)(n0 + ty4 + i) * cE + k0 + tx] = f2b(t[tx][ty4 + i]);
}

// fp32 -> bf16 elementwise (n multiple of 4)
__global__ __launch_bounds__(256) void cast_bf16_kernel(
    const float* __restrict__ in, unsigned short* __restrict__ out, int n4)
{
    for (int i = blockIdx.x * blockDim.x + threadIdx.x; i < n4;
         i += gridDim.x * blockDim.x) {
        float4 v = ((const float4*)in)[i];
        u16x4 o;
        o[0] = f2b(v.x); o[1] = f2b(v.y); o[2] = f2b(v.z); o[3] = f2b(v.w);
        *(u16x4*)(out + (size_t)i * 4) = o;
    }
}

// ---------------------------------------------------------------------------
// residual + layernorm: out = LN(X + R) * gamma + beta  (fp32), optional bf16 copy
// ---------------------------------------------------------------------------
__global__ __launch_bounds__(256) void residual_ln_kernel(
    const float* __restrict__ X, const float* __restrict__ R,
    const float* __restrict__ gamma, const float* __restrict__ beta,
    float* __restrict__ out, unsigned short* __restrict__ outb)
{
    const int row = blockIdx.x;
    const size_t off = (size_t)row * cE;
    const int tid = threadIdx.x;

    float v[3];
    float s = 0.f, ss = 0.f;
    #pragma unroll
    for (int i = 0; i < 3; ++i) {
        const int e = tid + i * 256;
        const float t = X[off + e] + R[off + e];
        v[i] = t; s += t; ss += t * t;
    }
    #pragma unroll
    for (int o = 32; o > 0; o >>= 1) {
        s  += __shfl_down(s, o);
        ss += __shfl_down(ss, o);
    }
    __shared__ float rs[4], rss[4];
    const int wid = tid >> 6;
    if ((tid & 63) == 0) { rs[wid] = s; rss[wid] = ss; }
    __syncthreads();
    s  = rs[0] + rs[1] + rs[2] + rs[3];
    ss = rss[0] + rss[1] + rss[2] + rss[3];

    const float mean = s * (1.f / cE);
    const float var  = ss * (1.f / cE) - mean * mean;
    const float inv  = rsqrtf(var + cEPS);
    #pragma unroll
    for (int i = 0; i < 3; ++i) {
        const int e = tid + i * 256;
        const float r = (v[i] - mean) * inv * gamma[e] + beta[e];
        out[off + e] = r;
        if (outb) outb[off + e] = f2b(r);
    }
}

// ---------------------------------------------------------------------------
// Spatial attention, MFMA flash version (verified round 4).
// ---------------------------------------------------------------------------
__global__ __launch_bounds__(256) void spatial_attn_mfma_kernel(
    const unsigned short* __restrict__ Q, const unsigned short* __restrict__ K,
    const unsigned short* __restrict__ V, unsigned short* __restrict__ O)
{
    __shared__ short Ks[64 * 64];      // [j][d] swizzled, row 128B
    __shared__ short Vt[64 * 64];      // [d][j] swizzled
    __shared__ short Ps[4][64 * 64];   // per-wave [q][j] swizzled

    const int bid = blockIdx.x;        // b*T*H + t*H + h
    const int h  = bid % cH;
    const int bt = bid / cH;
    const size_t base = (size_t)bt * cP * cE + h * cD;

    const int tid = threadIdx.x;
    const int w = tid >> 6, l = tid & 63;
    const int l15 = l & 15, l16 = l >> 4;

    short8 qf[4][2];
    #pragma unroll
    for (int mf = 0; mf < 4; ++mf)
        #pragma unroll
        for (int kf = 0; kf < 2; ++kf)
            qf[mf][kf] = *(const short8*)(
                Q + base + (size_t)(w * 64 + mf * 16 + l15) * cE + kf * 32 + l16 * 8);

    f32x4 o[4][4];
    float mrun[4][4], lrun[4][4];
    #pragma unroll
    for (int mf = 0; mf < 4; ++mf)
        #pragma unroll
        for (int j = 0; j < 4; ++j) {
            #pragma unroll
            for (int r = 0; r < 4; ++r) o[mf][j][r] = 0.f;
            mrun[mf][j] = -INFINITY; lrun[mf][j] = 0.f;
        }

    const int krow = w * 8 + (l >> 3);
    const int kc16 = l & 7;
    const int vj  = tid & 31;
    const int vd0 = (tid >> 5) * 8;

    for (int c0 = 0; c0 < cP; c0 += 64) {
        __syncthreads();
        #pragma unroll
        for (int p = 0; p < 2; ++p) {
            const int row = p * 32 + krow;
            gload16(K + base + (size_t)(c0 + row) * cE + ((kc16 ^ (row & 7)) << 3),
                    Ks + row * 64 + kc16 * 8);
        }
        #pragma unroll
        for (int p = 0; p < 2; ++p) {
            const int j = p * 32 + vj;
            short8 vv = *(const short8*)(V + base + (size_t)(c0 + j) * cE + vd0);
            char* vb = (char*)Vt;
            #pragma unroll
            for (int e = 0; e < 8; ++e) {
                const int row = vd0 + e;
                *(short*)(vb + row * 128 + ((2 * j) ^ ((row & 7) << 4))) = vv[e];
            }
        }
        __syncthreads();

        f32x4 s[4][4];
        #pragma unroll
        for (int mf = 0; mf < 4; ++mf)
            #pragma unroll
            for (int nf = 0; nf < 4; ++nf)
                #pragma unroll
                for (int r = 0; r < 4; ++r) s[mf][nf][r] = 0.f;

        #pragma unroll
        for (int nf = 0; nf < 4; ++nf) {
            const int row = nf * 16 + l15;
            const char* kb = (const char*)Ks + row * 128;
            const int sw = (row & 7) << 4;
            short8 k0 = *(const short8*)(kb + ((l16 * 16) ^ sw));
            short8 k1 = *(const short8*)(kb + ((64 + l16 * 16) ^ sw));
            #pragma unroll
            for (int mf = 0; mf < 4; ++mf) {
                s[mf][nf] = __builtin_amdgcn_mfma_f32_16x16x32_bf16(qf[mf][0], k0, s[mf][nf], 0, 0, 0);
                s[mf][nf] = __builtin_amdgcn_mfma_f32_16x16x32_bf16(qf[mf][1], k1, s[mf][nf], 0, 0, 0);
            }
        }

        #pragma unroll
        for (int mf = 0; mf < 4; ++mf)
            #pragma unroll
            for (int nf = 0; nf < 4; ++nf)
                #pragma unroll
                for (int r = 0; r < 4; ++r) s[mf][nf][r] *= cSCALE;

        #pragma unroll
        for (int mf = 0; mf < 4; ++mf) {
            #pragma unroll
            for (int r = 0; r < 4; ++r) {
                float rv = fmaxf(fmaxf(s[mf][0][r], s[mf][1][r]),
                                 fmaxf(s[mf][2][r], s[mf][3][r]));
                rv = fmaxf(rv, __shfl_xor(rv, 1));
                rv = fmaxf(rv, __shfl_xor(rv, 2));
                rv = fmaxf(rv, __shfl_xor(rv, 4));
                rv = fmaxf(rv, __shfl_xor(rv, 8));
                const float mn = fmaxf(mrun[mf][r], rv);
                const float al = __expf(mrun[mf][r] - mn);
                mrun[mf][r] = mn;
                float ps = 0.f;
                #pragma unroll
                for (int nf = 0; nf < 4; ++nf) {
                    const float pe = __expf(s[mf][nf][r] - mn);
                    s[mf][nf][r] = pe;
                    ps += pe;
                }
                ps += __shfl_xor(ps, 1);
                ps += __shfl_xor(ps, 2);
                ps += __shfl_xor(ps, 4);
                ps += __shfl_xor(ps, 8);
                lrun[mf][r] = lrun[mf][r] * al + ps;
                #pragma unroll
                for (int df = 0; df < 4; ++df) o[mf][df][r] *= al;
            }
        }

        char* pw = (char*)&Ps[w][0];
        #pragma unroll
        for (int mf = 0; mf < 4; ++mf)
            #pragma unroll
            for (int nf = 0; nf < 4; ++nf)
                #pragma unroll
                for (int r = 0; r < 4; ++r) {
                    const int row = mf * 16 + l16 * 4 + r;
                    *(short*)(pw + row * 128 + (((nf * 16 + l15) * 2) ^ ((row & 7) << 4))) =
                        (short)f2b(s[mf][nf][r]);
                }

        short8 pa[4][2];
        #pragma unroll
        for (int mf = 0; mf < 4; ++mf) {
            const int prow = mf * 16 + l15;
            const char* pb = (const char*)&Ps[w][0] + prow * 128;
            const int sw = (prow & 7) << 4;
            pa[mf][0] = *(const short8*)(pb + ((l16 * 16) ^ sw));
            pa[mf][1] = *(const short8*)(pb + ((64 + l16 * 16) ^ sw));
        }
        #pragma unroll
        for (int df = 0; df < 4; ++df) {
            const int vrow = df * 16 + l15;
            const char* vbb = (const char*)Vt + vrow * 128;
            const int sw = (vrow & 7) << 4;
            short8 v0 = *(const short8*)(vbb + ((l16 * 16) ^ sw));
            short8 v1 = *(const short8*)(vbb + ((64 + l16 * 16) ^ sw));
            #pragma unroll
            for (int mf = 0; mf < 4; ++mf) {
                o[mf][df] = __builtin_amdgcn_mfma_f32_16x16x32_bf16(pa[mf][0], v0, o[mf][df], 0, 0, 0);
                o[mf][df] = __builtin_amdgcn_mfma_f32_16x16x32_bf16(pa[mf][1], v1, o[mf][df], 0, 0, 0);
            }
        }
    }

    #pragma unroll
    for (int mf = 0; mf < 4; ++mf)
        #pragma unroll
        for (int r = 0; r < 4; ++r) {
            const float inv = 1.f / lrun[mf][r];
            const size_t rowoff = base + (size_t)(w * 64 + mf * 16 + l16 * 4 + r) * cE;
            #pragma unroll
            for (int df = 0; df < 4; ++df)
                O[rowoff + df * 16 + l15] = f2b(o[mf][df][r] * inv);
        }
}

// ---------------------------------------------------------------------------
// Temporal causal attention (bf16 I/O): per (b,p,head-group of 6). T=16.
// ---------------------------------------------------------------------------
__global__ __launch_bounds__(128) void temporal_attn_kernel(
    const unsigned short* __restrict__ Q, const unsigned short* __restrict__ Kb,
    const unsigned short* __restrict__ V, unsigned short* __restrict__ O)
{
    const int bid = blockIdx.x;          // (b*P + p)*2 + hg
    const int hg  = bid & 1;
    const int bp  = bid >> 1;
    const int p   = bp % cP;
    const int b   = bp / cP;

    __shared__ float Ks[cT][6][cD + 1];
    __shared__ float Vs[cT][6][cD + 1];

    const size_t framestride = (size_t)cP * cE;
    const size_t base0 = ((size_t)(b * cT) * cP + p) * cE + hg * 384;

    for (int li = threadIdx.x; li < cT * 384; li += 128) {
        const int s = li / 384;
        const int r = li % 384;
        const size_t src = base0 + (size_t)s * framestride + r;
        Ks[s][r / 64][r & 63] = b2f(Kb[src]);
        Vs[s][r / 64][r & 63] = b2f(V[src]);
    }
    __syncthreads();
    if (threadIdx.x >= 96) return;

    const int hh = threadIdx.x >> 4;
    const int t  = threadIdx.x & 15;
    const size_t qoff = ((size_t)(b * cT + t) * cP + p) * cE + hg * 384 + hh * cD;

    float q[cD];
    #pragma unroll
    for (int d = 0; d < cD; d += 8) {
        short8 f = *(const short8*)(Q + qoff + d);
        #pragma unroll
        for (int j = 0; j < 8; ++j) q[d + j] = b2f((unsigned short)f[j]);
    }

    float sc[cT];
    float mx = -INFINITY;
    #pragma unroll
    for (int s = 0; s < cT; ++s) {
        float acc = 0.f;
        #pragma unroll
        for (int d = 0; d < cD; ++d) acc = fmaf(q[d], Ks[s][hh][d], acc);
        sc[s] = (s <= t) ? acc * cSCALE : -INFINITY;
        mx = fmaxf(mx, sc[s]);
    }
    float l = 0.f;
    #pragma unroll
    for (int s = 0; s < cT; ++s) {
        const float e_ = __expf(sc[s] - mx);
        sc[s] = e_;
        l += e_;
    }
    float o[cD];
    #pragma unroll
    for (int d = 0; d < cD; ++d) o[d] = 0.f;
    #pragma unroll
    for (int s = 0; s < cT; ++s) {
        const float pj = sc[s];
        #pragma unroll
        for (int d = 0; d < cD; ++d) o[d] = fmaf(pj, Vs[s][hh][d], o[d]);
    }
    const float invl = 1.f / l;
    unsigned short* op = O + qoff;
    #pragma unroll
    for (int d = 0; d < cD; d += 8) {
        u16x8 f;
        #pragma unroll
        for (int j = 0; j < 8; ++j) f[j] = f2b(o[d + j] * invl);
        *(u16x8*)(op + d) = f;
    }
}

// ---------------------------------------------------------------------------
extern "C" void kernel_launch(void* const* d_in, const int* in_sizes, int n_in,
                              void* d_out, int out_size, void* d_ws, size_t ws_size,
                              hipStream_t stream)
{
    const float* x    = (const float*)d_in[0];
    const float* sq_w = (const float*)d_in[1];
    const float* sk_w = (const float*)d_in[2];
    const float* sv_w = (const float*)d_in[3];
    const float* so_w = (const float*)d_in[4];
    const float* sq_b = (const float*)d_in[5];
    const float* sk_b = (const float*)d_in[6];
    const float* sv_b = (const float*)d_in[7];
    const float* so_b = (const float*)d_in[8];
    const float* sg   = (const float*)d_in[9];
    const float* sb   = (const float*)d_in[10];
    const float* tq_w = (const float*)d_in[11];
    const float* tk_w = (const float*)d_in[12];
    const float* tv_w = (const float*)d_in[13];
    const float* to_w = (const float*)d_in[14];
    const float* tq_b = (const float*)d_in[15];
    const float* tk_b = (const float*)d_in[16];
    const float* tv_b = (const float*)d_in[17];
    const float* to_b = (const float*)d_in[18];
    const float* tg   = (const float*)d_in[19];
    const float* tb   = (const float*)d_in[20];
    const float* w1   = (const float*)d_in[21];
    const float* b1   = (const float*)d_in[22];
    const float* w2   = (const float*)d_in[23];
    const float* b2   = (const float*)d_in[24];
    const float* g    = (const float*)d_in[25];
    const float* bb   = (const float*)d_in[26];

    const size_t NE = (size_t)NTOK * cE;   // 12.58M elements
    const size_t EE = (size_t)cE * cE;     // 589824

    // workspace layout (~245 MB)
    float* W0 = (float*)d_ws;                    // fp32 residual stream [NE]
    float* Wp = W0 + NE;                         // fp32 proj / ffn out  [NE]
    unsigned short* Xb = (unsigned short*)(Wp + NE);  // bf16 x_cur [NE]
    unsigned short* Qb = Xb + NE;
    unsigned short* Kbuf = Qb + NE;
    unsigned short* Vb = Kbuf + NE;
    unsigned short* Ob = Vb + NE;
    unsigned short* Hb = Qb;                     // bf16 hidden [NTOK*DFF] overlays Qb..Ob
    unsigned short* WT = Ob + NE;                // bf16 transposed weights
    unsigned short* sqT = WT;                    // [sq;sk;sv] contiguous -> QKV fused B
    unsigned short* skT = sqT + EE;
    unsigned short* svT = skT + EE;
    unsigned short* soT = svT + EE;
    unsigned short* tqT = soT + EE;              // [tq;tk;tv] contiguous
    unsigned short* tkT = tqT + EE;
    unsigned short* tvT = tkT + EE;
    unsigned short* toT = tvT + EE;
    unsigned short* w1T = toT + EE;              // [DFF][E]
    unsigned short* w2T = w1T + (size_t)cDFF * cE;  // [E][DFF]

    const dim3 blk(256);
    const dim3 blk512(512);
    const dim3 gLN(NTOK);
    const dim3 gQKV(1152);       // (16384/256) * (2304/128)
    const dim3 gOUT(384);        // 64 * (768/128)
    const dim3 gFF1(1536);       // 64 * (3072/128)

    // ---- prep: cast x, transpose+cast all weights to bf16 [N][K] ----
    cast_bf16_kernel<<<dim3(2048), blk, 0, stream>>>(x, Xb, (int)(NE / 4));
    {
        TP8 p;
        p.src[0] = sq_w; p.dst[0] = sqT;
        p.src[1] = sk_w; p.dst[1] = skT;
        p.src[2] = sv_w; p.dst[2] = svT;
        p.src[3] = so_w; p.dst[3] = soT;
        p.src[4] = tq_w; p.dst[4] = tqT;
        p.src[5] = tk_w; p.dst[5] = tkT;
        p.src[6] = tv_w; p.dst[6] = tvT;
        p.src[7] = to_w; p.dst[7] = toT;
        transpose_cast8_kernel<<<dim3(cE / 32, cE / 32, 8), blk, 0, stream>>>(p);
    }
    transpose_cast_kernel<<<dim3(cDFF / 32, cE / 32), blk, 0, stream>>>(w1, w1T, cE, cDFF);
    transpose_cast_kernel<<<dim3(cE / 32, cDFF / 32), blk, 0, stream>>>(w2, w2T, cDFF, cE);

    // ---- Spatial attention block ----
    gemm256_kernel<1,0,1><<<gQKV, blk512, 0, stream>>>(
        Xb, sqT, sq_b, sk_b, sv_b, Qb, Kbuf, Vb, NTOK, 2304, cE, 18);
    spatial_attn_mfma_kernel<<<dim3(cB * cT * cH), blk, 0, stream>>>(Qb, Kbuf, Vb, Ob);
    gemm256_kernel<0,0,0><<<gOUT, blk512, 0, stream>>>(
        Ob, soT, so_b, nullptr, nullptr, Wp, nullptr, nullptr, NTOK, cE, cE, 6);
    residual_ln_kernel<<<gLN, blk, 0, stream>>>(x, Wp, sg, sb, W0, Xb);

    // ---- Temporal attention block ----
    gemm256_kernel<1,0,1><<<gQKV, blk512, 0, stream>>>(
        Xb, tqT, tq_b, tk_b, tv_b, Qb, Kbuf, Vb, NTOK, 2304, cE, 18);
    temporal_attn_kernel<<<dim3(cB * cP * 2), dim3(128), 0, stream>>>(Qb, Kbuf, Vb, Ob);
    gemm256_kernel<0,0,0><<<gOUT, blk512, 0, stream>>>(
        Ob, toT, to_b, nullptr, nullptr, Wp, nullptr, nullptr, NTOK, cE, cE, 6);
    residual_ln_kernel<<<gLN, blk, 0, stream>>>(W0, Wp, tg, tb, W0, Xb);

    // ---- FFN ----
    gemm256_kernel<1,1,0><<<gFF1, blk512, 0, stream>>>(
        Xb, w1T, b1, nullptr, nullptr, Hb, nullptr, nullptr, NTOK, cDFF, cE, 24);
    gemm256_kernel<0,0,0><<<gOUT, blk512, 0, stream>>>(
        Hb, w2T, b2, nullptr, nullptr, Wp, nullptr, nullptr, NTOK, cE, cDFF, 6);
    residual_ln_kernel<<<gLN, blk, 0, stream>>>(W0, Wp, g, bb, (float*)d_out, nullptr);
}